// Round 8
// baseline (310.592 us; speedup 1.0000x reference)
//
#include <hip/hip_runtime.h>
#include <cstdint>
#include <cstddef>

typedef __bf16 bf16x8 __attribute__((ext_vector_type(8)));
typedef __bf16 bf16x4 __attribute__((ext_vector_type(4)));
typedef float f32x4 __attribute__((ext_vector_type(4)));

// ---------------------------------------------------------------------------
// Problem constants (B=1): D=2048, NH=16, DH=128, DC=512, DCQ=1024, L=2048
// ---------------------------------------------------------------------------

template <int N> __device__ __forceinline__ void waitcnt_vm() {
  if constexpr (N == 3)      asm volatile("s_waitcnt vmcnt(3)" ::: "memory");
  else if constexpr (N == 4) asm volatile("s_waitcnt vmcnt(4)" ::: "memory");
  else if constexpr (N == 6) asm volatile("s_waitcnt vmcnt(6)" ::: "memory");
  else if constexpr (N == 8) asm volatile("s_waitcnt vmcnt(8)" ::: "memory");
  else                       asm volatile("s_waitcnt vmcnt(0)" ::: "memory");
}

// ---------------------------------------------------------------------------
// MFMA GEMM core: acc(BMx128) += A(M,K) @ Bt(N,K)^T tile.  A,Bt row-major
// bf16.  BK = 32*NKS, 4 waves, double-buffered LDS + counted-vmcnt pipeline.
// On return: all waves have passed the trailing barrier (LDS reusable).
//  BM=128: waves 2x2 over (128,128), wave 64x64 (acc 4x4).
//  BM=64:  waves 2x2 over (64,128),  wave 32x64 (acc 2x4).
// ---------------------------------------------------------------------------
template <int BM, int NKS>
__device__ __forceinline__ void gemm_core(const __bf16* __restrict__ A,
                                          const __bf16* __restrict__ Bt,
                                          int K, int bm, int bn,
                                          __bf16* As, __bf16* Bs,
                                          f32x4 (*acc)[4]) {
  const int tid = threadIdx.x;
  const int w = tid >> 6;
  const int lane = tid & 63;
  const int quad = lane >> 4;
  const int l16 = lane & 15;
  constexpr int WM = (BM == 128) ? 64 : 32;   // wave M extent
  constexpr int MI = WM / 16;                 // acc rows (4 or 2)
  constexpr int NL = NKS * (BM / 64 + 2);     // loads/wave per stage
  const int wm = (w & 1) * WM;
  const int wn = (w >> 1) * 64;
  const int srow = lane >> 2;
  const int sseg = (lane & 3) * 8;

  // stage one BK-wide K-slice into LDS buffer `buf` (async, NL loads/wave)
  auto stage = [&](int k0, int buf) {
#pragma unroll
    for (int ks = 0; ks < NKS; ++ks) {
#pragma unroll
      for (int g = 0; g < BM / 64; ++g) {     // A: BM rows
        const int grp = w + g * 4;
        const __bf16* ga = A + (size_t)(bm + grp * 16 + srow) * K + k0 + ks * 32 + sseg;
        __builtin_amdgcn_global_load_lds(
            (const __attribute__((address_space(1))) void*)ga,
            (__attribute__((address_space(3))) void*)&As[(buf * NKS + ks) * (BM * 32) + grp * 512],
            16, 0, 0);
      }
#pragma unroll
      for (int g = 0; g < 2; ++g) {           // B: always 128 rows
        const int grp = w + g * 4;
        const __bf16* gb = Bt + (size_t)(bn + grp * 16 + srow) * K + k0 + ks * 32 + sseg;
        __builtin_amdgcn_global_load_lds(
            (const __attribute__((address_space(1))) void*)gb,
            (__attribute__((address_space(3))) void*)&Bs[(buf * NKS + ks) * 4096 + grp * 512],
            16, 0, 0);
      }
    }
  };

#pragma unroll
  for (int i = 0; i < MI; ++i)
#pragma unroll
    for (int j = 0; j < 4; ++j) acc[i][j] = (f32x4){0.f, 0.f, 0.f, 0.f};

  // Drain any prologue VMEM so vmcnt counts only staging traffic.
  asm volatile("s_waitcnt vmcnt(0)" ::: "memory");
  stage(0, 0);

  const int NIT = K / (32 * NKS);
  for (int it = 0; it < NIT; ++it) {
    const int cur = it & 1;
    if (it + 1 < NIT) {
      stage((it + 1) * 32 * NKS, cur ^ 1);
      waitcnt_vm<NL>();                // cur's NL loads done; next's in flight
    } else {
      waitcnt_vm<0>();
    }
    __builtin_amdgcn_s_barrier();      // all waves' cur tiles staged
    asm volatile("" ::: "memory");     // pin LDS reads below the barrier
    const __bf16* Ab = &As[cur * NKS * (BM * 32)];
    const __bf16* Bb = &Bs[cur * NKS * 4096];
#pragma unroll
    for (int ks = 0; ks < NKS; ++ks) {
      bf16x8 af[MI], bfr[4];
#pragma unroll
      for (int i = 0; i < MI; ++i)
        af[i] = *(const bf16x8*)&Ab[ks * (BM * 32) + (wm + i * 16 + l16) * 32 + quad * 8];
#pragma unroll
      for (int j = 0; j < 4; ++j)
        bfr[j] = *(const bf16x8*)&Bb[ks * 4096 + (wn + j * 16 + l16) * 32 + quad * 8];
#pragma unroll
      for (int i = 0; i < MI; ++i)
#pragma unroll
        for (int j = 0; j < 4; ++j)
          acc[i][j] = __builtin_amdgcn_mfma_f32_16x16x32_bf16(af[i], bfr[j],
                                                              acc[i][j], 0, 0, 0);
    }
    // own LDS reads done, then free buf(cur) for stage(it+2)
    asm volatile("s_waitcnt lgkmcnt(0)" ::: "memory");
    __builtin_amdgcn_s_barrier();
    asm volatile("" ::: "memory");
  }
}

// plain epilogue: store acc to C (bf16 or f32), row-major ldc = N
template <int BM, int NKS, bool BF16OUT>
__device__ __forceinline__ void gemm_body(const __bf16* __restrict__ A,
                                          const __bf16* __restrict__ Bt,
                                          void* __restrict__ Cv,
                                          int N, int K, int bm, int bn,
                                          __bf16* As, __bf16* Bs) {
  constexpr int MI = (BM == 128) ? 4 : 2;
  constexpr int WM = (BM == 128) ? 64 : 32;
  f32x4 acc[MI][4];
  gemm_core<BM, NKS>(A, Bt, K, bm, bn, As, Bs, acc);
  const int tid = threadIdx.x;
  const int w = tid >> 6, lane = tid & 63, quad = lane >> 4, l16 = lane & 15;
  const int wm = (w & 1) * WM, wn = (w >> 1) * 64;
#pragma unroll
  for (int i = 0; i < MI; ++i)
#pragma unroll
    for (int j = 0; j < 4; ++j)
#pragma unroll
      for (int r = 0; r < 4; ++r) {
        const int row = bm + wm + i * 16 + quad * 4 + r;
        const int col = bn + wn + j * 16 + l16;
        if constexpr (BF16OUT)
          ((__bf16*)Cv)[(size_t)row * N + col] = (__bf16)acc[i][j][r];
        else
          ((float*)Cv)[(size_t)row * N + col] = acc[i][j][r];
      }
}

template <int BM, int NKS, bool BF16OUT>
__global__ __launch_bounds__(256) void gemm_mfma(const __bf16* __restrict__ A,
                                                 const __bf16* __restrict__ Bt,
                                                 void* __restrict__ Cv,
                                                 int M, int N, int K) {
  __shared__ __bf16 As[2 * BM * 32 * NKS];
  __shared__ __bf16 Bs[2 * 128 * 32 * NKS];
  gemm_body<BM, NKS, BF16OUT>(A, Bt, Cv, N, K, blockIdx.y * BM, blockIdx.x * 128, As, Bs);
}

// ---------------------------------------------------------------------------
// down_lam: down-projections (DKV 4 col-tiles + DQ 8 col-tiles, BM=64 BK=64)
// + lam (sigmoid(x.W_lam+b), MFMA N=16) fused in one launch.
// Grid dim3(13, 32): bx<4 DKV, bx<12 DQ, bx==12 lam rows by*64..+63.
// ---------------------------------------------------------------------------
__global__ __launch_bounds__(256) void down_lam(
    const __bf16* __restrict__ x_bf, const __bf16* __restrict__ WtDKV,
    const __bf16* __restrict__ WtDQ, __bf16* __restrict__ c_kv,
    __bf16* __restrict__ c_q, const __bf16* __restrict__ WlT,
    const float* __restrict__ b_lam, float* __restrict__ lam) {
  __shared__ __bf16 As[2 * 64 * 32 * 2];     // 16 KB
  __shared__ __bf16 Bs[2 * 128 * 32 * 2];    // 32 KB
  const int bx = blockIdx.x;
  const int tid = threadIdx.x;
  if (bx == 12) {  // lam: rows by*64..+63 (w picks 16-row group)
    const int w = tid >> 6, lane = tid & 63, quad = lane >> 4, l16 = lane & 15;
    const int m0 = (blockIdx.y * 4 + w) * 16;
    const __bf16* xrow = x_bf + (size_t)(m0 + l16) * 2048 + quad * 8;
    const __bf16* wrow = WlT + (size_t)l16 * 2048 + quad * 8;
    f32x4 acc[4];
#pragma unroll
    for (int u = 0; u < 4; ++u) acc[u] = (f32x4){0.f, 0.f, 0.f, 0.f};
    for (int k0 = 0; k0 < 2048; k0 += 128) {
#pragma unroll
      for (int u = 0; u < 4; ++u) {
        bf16x8 a = *(const bf16x8*)&xrow[k0 + u * 32];
        bf16x8 b = *(const bf16x8*)&wrow[k0 + u * 32];
        acc[u] = __builtin_amdgcn_mfma_f32_16x16x32_bf16(a, b, acc[u], 0, 0, 0);
      }
    }
    const float bl = b_lam[l16];
#pragma unroll
    for (int r = 0; r < 4; ++r) {
      const float v = acc[0][r] + acc[1][r] + acc[2][r] + acc[3][r] + bl;
      lam[(size_t)(m0 + quad * 4 + r) * 16 + l16] = 1.0f / (1.0f + __expf(-v));
    }
    return;
  }
  if (bx < 4)
    gemm_body<64, 2, true>(x_bf, WtDKV, (void*)c_kv, 512, 2048,
                           blockIdx.y * 64, bx * 128, As, Bs);
  else
    gemm_body<64, 2, true>(x_bf, WtDQ, (void*)c_q, 1024, 2048,
                           blockIdx.y * 64, (bx - 4) * 128, As, Bs);
}

// ---------------------------------------------------------------------------
// up_fused3: up-projections UK/UV/UQ (BM=128 BK=32) with fused epilogues.
//  UK (bx<16):  K-RoPE applied in-epilogue (pairs d<->d^64 exchanged via a
//               32 KB LDS bf16 stash — bit-identical to the old separate
//               rope pass, which also roped bf16-rounded values).
//  UV (bx<32):  V written directly TRANSPOSED to v_t[d][l] (acc's 4
//               consecutive rows = 8 B contiguous in transposed layout).
//  UQ (else):   plain bf16 store to q_bf (roped later in attn, unchanged).
// Replaces the ropek_transv kernel and the k/v round trips entirely.
// Grid dim3(64, 16).
// ---------------------------------------------------------------------------
__global__ __launch_bounds__(256) void up_fused3(
    const __bf16* __restrict__ c_kv, const __bf16* __restrict__ WtUK,
    const __bf16* __restrict__ WtUV, const __bf16* __restrict__ c_q,
    const __bf16* __restrict__ WtUQ, __bf16* __restrict__ k_bf,
    __bf16* __restrict__ v_t, __bf16* __restrict__ q_bf,
    const float* __restrict__ cosT, const float* __restrict__ sinT) {
  __shared__ __align__(16) char usm[32768];
  __bf16* As = (__bf16*)usm;             // 16 KB (2 buf x 128x32)
  __bf16* Bs = (__bf16*)(usm + 16384);   // 16 KB
  const int bx = blockIdx.x;
  const int bm = blockIdx.y * 128;
  const int tid = threadIdx.x;
  const int w = tid >> 6, lane = tid & 63, quad = lane >> 4, l16 = lane & 15;
  const int wm = (w & 1) * 64, wn = (w >> 1) * 64;
  f32x4 acc[4][4];
  if (bx < 16) {          // ---- UK -> roped K ----
    const int bn = bx * 128;   // head-aligned (128-wide heads)
    gemm_core<128, 1>(c_kv, WtUK, 512, bm, bn, As, Bs, acc);
    // gemm_core's trailing barrier freed usm; stash bf16 tile for pairs
    __bf16 (*Kt)[128] = (__bf16(*)[128])usm;
#pragma unroll
    for (int i = 0; i < 4; ++i)
#pragma unroll
      for (int j = 0; j < 4; ++j)
#pragma unroll
        for (int r = 0; r < 4; ++r)
          Kt[wm + i * 16 + quad * 4 + r][wn + j * 16 + l16] = (__bf16)acc[i][j][r];
    __syncthreads();
#pragma unroll
    for (int j = 0; j < 4; ++j) {
      const int d = wn + j * 16 + l16;
      const float sgn = (d < 64) ? -1.f : 1.f;
#pragma unroll
      for (int i = 0; i < 4; ++i)
#pragma unroll
        for (int r = 0; r < 4; ++r) {
          const int lr = wm + i * 16 + quad * 4 + r;
          const int l = bm + lr;
          const float v = (float)Kt[lr][d];        // == bf16(acc), as before
          const float pr = (float)Kt[lr][d ^ 64];
          const float ov = v * cosT[l * 128 + d] + sgn * pr * sinT[l * 128 + d];
          k_bf[(size_t)l * 2048 + bn + d] = (__bf16)ov;
        }
    }
  } else if (bx < 32) {   // ---- UV -> transposed V ----
    const int bn = (bx - 16) * 128;
    gemm_core<128, 1>(c_kv, WtUV, 512, bm, bn, As, Bs, acc);
#pragma unroll
    for (int i = 0; i < 4; ++i)
#pragma unroll
      for (int j = 0; j < 4; ++j) {
        const int d = bn + wn + j * 16 + l16;       // global dim = v_t row
        const int l = bm + wm + i * 16 + quad * 4;  // 4 consecutive l
        bf16x4 pk = {(__bf16)acc[i][j][0], (__bf16)acc[i][j][1],
                     (__bf16)acc[i][j][2], (__bf16)acc[i][j][3]};
        *(bf16x4*)&v_t[(size_t)d * 2048 + l] = pk;
      }
  } else {                // ---- UQ -> plain q_bf ----
    const int bn = (bx - 32) * 128;
    gemm_core<128, 1>(c_q, WtUQ, 1024, bm, bn, As, Bs, acc);
#pragma unroll
    for (int i = 0; i < 4; ++i)
#pragma unroll
      for (int j = 0; j < 4; ++j)
#pragma unroll
        for (int r = 0; r < 4; ++r) {
          const int row = bm + wm + i * 16 + quad * 4 + r;
          const int col = bn + wn + j * 16 + l16;
          q_bf[(size_t)row * 4096 + col] = (__bf16)acc[i][j][r];
        }
  }
}

// ---------------------------------------------------------------------------
// prep_all: all weight transposes (fp32 (K,N) -> bf16 (N,K), 32x32 tiles),
// x cast, rope tables, W_lam transpose — one launch.
// ---------------------------------------------------------------------------
__global__ __launch_bounds__(256) void prep_all(
    const float* __restrict__ W_DKV, const float* __restrict__ W_DQ,
    const float* __restrict__ W_UK,  const float* __restrict__ W_UV,
    const float* __restrict__ W_UQ,  const float* __restrict__ W_out,
    const float* __restrict__ x,     const float* __restrict__ W_lam,
    __bf16* __restrict__ tDKV, __bf16* __restrict__ tDQ,
    __bf16* __restrict__ tUK,  __bf16* __restrict__ tUV,
    __bf16* __restrict__ tUQ,  __bf16* __restrict__ tOut,
    __bf16* __restrict__ x_bf, __bf16* __restrict__ WlT,
    float* __restrict__ cosT, float* __restrict__ sinT) {
  __shared__ float T[32][36];
  int t = blockIdx.x;
  const int tid = threadIdx.x;
  if (t < 13312) {
    const float* src; __bf16* dst; int K, N, kx, ny;
    if (t < 1024)      {            src = W_DKV; dst = tDKV; K = 2048; N = 512;  kx = t & 63; ny = t >> 6; }
    else if (t < 3072) { t -= 1024; src = W_DQ;  dst = tDQ;  K = 2048; N = 1024; kx = t & 63; ny = t >> 6; }
    else if (t < 4096) { t -= 3072; src = W_UK;  dst = tUK;  K = 512;  N = 2048; kx = t & 15; ny = t >> 4; }
    else if (t < 5120) { t -= 4096; src = W_UV;  dst = tUV;  K = 512;  N = 2048; kx = t & 15; ny = t >> 4; }
    else if (t < 9216) { t -= 5120; src = W_UQ;  dst = tUQ;  K = 1024; N = 4096; kx = t & 31; ny = t >> 5; }
    else               { t -= 9216; src = W_out; dst = tOut; K = 2048; N = 2048; kx = t & 63; ny = t >> 6; }
    const int k0 = kx * 32;
    const int n0 = ny * 32;
    const int r = tid >> 3;
    const int c = (tid & 7) * 4;
    *(float4*)&T[r][c] = *(const float4*)&src[(size_t)(k0 + r) * N + n0 + c];
    __syncthreads();
    bf16x4 o = {(__bf16)T[c + 0][r], (__bf16)T[c + 1][r],
                (__bf16)T[c + 2][r], (__bf16)T[c + 3][r]};
    *(bf16x4*)&dst[(size_t)(n0 + r) * K + k0 + c] = o;
    return;
  }
  t -= 13312;
  if (t < 4096) {  // x cast: 4096 blocks x 1024 floats
    const int i = t * 256 + tid;
    float4 v = *(const float4*)&x[(size_t)i * 4];
    bf16x4 o = {(__bf16)v.x, (__bf16)v.y, (__bf16)v.z, (__bf16)v.w};
    *(bf16x4*)&x_bf[(size_t)i * 4] = o;
    return;
  }
  t -= 4096;
  if (t < 1024) {  // rope tables: 2 rows per block
    const int l = t * 2 + (tid >> 7);
    const int d = tid & 127;
    const int j = d & 63;
    const float inv = exp2f(-(float)j * 0.2076205059304601f);  // log2(1e4)/64
    const float ang = (float)l * inv;
    cosT[l * 128 + d] = cosf(ang);
    sinT[l * 128 + d] = sinf(ang);
    return;
  }
  t -= 1024;
  {  // W_lam (2048,16) -> WlT (16,2048) bf16: 128 blocks
    const int i = t * 256 + tid;
    const int k = i >> 4, n = i & 15;
    WlT[(size_t)n * 2048 + k] = (__bf16)W_lam[i];
  }
}

// ---------------------------------------------------------------------------
// MFMA flash attention, 512-thread blocks (8 waves), double-buffered K/V,
// counted-vmcnt pipeline + setprio.  Wave w (0..7) owns 16 q-rows of head
// (w>>2) — 16 waves/CU = 4/SIMD in pair regime.  Strict-descending qt
// dispatch (LPT).  Exact defer-rescale: skipped rescale has alpha==exp(0)==1.
//  Block = (kv-head hk, 64 q-rows).  Grid 512.
//  LDS = 81920 B (2 blocks/CU):
//    [0,32K)   buf0: Ks 64x128 (16K) + Vs^T 128x64 (16K), XOR-swizzled
//    [32K,64K) buf1: same
//    [64K,80K) P: per-wave 16 rows x 64 keys bf16 (2 KB each)
// ---------------------------------------------------------------------------
__global__ __launch_bounds__(512, 2) void attn_kernel3(
    const __bf16* __restrict__ Qb, const __bf16* __restrict__ Kb,
    const __bf16* __restrict__ Vt, const float* __restrict__ cosT,
    const float* __restrict__ sinT, const float* __restrict__ lam,
    __bf16* __restrict__ y) {
  __shared__ __align__(16) char smem[81920];
  float (*Ex)[132] = (float(*)[132])smem;              // epilogue union (33.8 KB)

  const int bx = blockIdx.x;
  const int qt = 31 - (bx >> 4);              // strict LPT: heavy first
  const int hk = bx & 15;
  const int q0 = qt * 64;
  const int tid = threadIdx.x;
  const int w = tid >> 6, lane = tid & 63, quad = lane >> 4, l16 = lane & 15;
  const int wrow = (w & 3) * 16;              // wave's 16-row group
  const int qoff = (2 * hk + (w >> 2)) * 128; // wave's q-head
  const int kvoff = hk * 128;
  const float qscale = 0.08838834764831845f;  // 1/sqrt(128), folded into Q
  char* Pw = smem + 65536 + w * 2048;         // 16 rows x 128 B per wave

  // ---- Q fragment + RoPE + scale in-register (one 16-row subtile) ----
  bf16x8 aq[4];
  {
    const int l = q0 + wrow + l16;
    const size_t qbase = (size_t)l * 4096 + qoff + quad * 8;
    bf16x8 raw[4];
#pragma unroll
    for (int ks = 0; ks < 4; ++ks)
      raw[ks] = *(const bf16x8*)&Qb[qbase + ks * 32];
#pragma unroll
    for (int ks = 0; ks < 4; ++ks) {
      const float* cp = &cosT[l * 128 + ks * 32 + quad * 8];
      const float* sp = &sinT[l * 128 + ks * 32 + quad * 8];
#pragma unroll
      for (int j = 0; j < 8; ++j) {
        const float cv = cp[j];
        const float sv = sp[j];
        const float rot = (ks < 2) ? -(float)raw[ks + 2][j] : (float)raw[ks - 2][j];
        aq[ks][j] = (__bf16)(((float)raw[ks][j] * cv + rot * sv) * qscale);
      }
    }
  }

  // ---- staging helper: 4 global_load_lds per wave into chosen buffer ----
  auto stage = [&](int kt_, char* buf) {
    const int k0_ = kt_ * 64;
    __bf16* Ksb = (__bf16*)buf;
    __bf16* Vsb = (__bf16*)(buf + 16384);
#pragma unroll
    for (int d = 0; d < 2; ++d) {
      const int r0 = w * 8 + d * 4;              // 4 K-rows per DMA
      const int row = r0 + (lane >> 4);
      const int ck = (lane & 15) ^ (row & 15);
      const __bf16* ga = Kb + (size_t)(k0_ + row) * 2048 + kvoff + ck * 8;
      __builtin_amdgcn_global_load_lds(
          (const __attribute__((address_space(1))) void*)ga,
          (__attribute__((address_space(3))) void*)&Ksb[r0 * 128], 16, 0, 0);
      const int r0v = w * 16 + d * 8;            // 8 V-rows per DMA
      const int rowv = r0v + (lane >> 3);
      const int cv = (lane & 7) ^ (rowv & 7);
      const __bf16* gv = Vt + (size_t)(kvoff + rowv) * 2048 + k0_ + cv * 8;
      __builtin_amdgcn_global_load_lds(
          (const __attribute__((address_space(1))) void*)gv,
          (__attribute__((address_space(3))) void*)&Vsb[r0v * 64], 16, 0, 0);
    }
  };

  f32x4 o[8];
#pragma unroll
  for (int i = 0; i < 8; ++i) o[i] = (f32x4){0.f, 0.f, 0.f, 0.f};
  float m = -1e30f, lsum = 0.f;

  // Drain Q/rope loads so vmcnt counts only staging traffic, then prologue.
  asm volatile("s_waitcnt vmcnt(0)" ::: "memory");
  stage(0, smem);

  for (int kt = 0; kt <= qt; ++kt) {
    const int cur = kt & 1;
    __bf16* Ks = (__bf16*)(smem + cur * 32768);
    __bf16* Vs = (__bf16*)(smem + cur * 32768 + 16384);
    const int k0 = kt * 64;
    if (kt < qt) {
      stage(kt + 1, smem + (cur ^ 1) * 32768);
      asm volatile("s_waitcnt vmcnt(4)" ::: "memory");  // kt's 4 loads done
    } else {
      asm volatile("s_waitcnt vmcnt(0)" ::: "memory");
    }
    __builtin_amdgcn_s_barrier();        // all waves' kt tiles staged
    asm volatile("" ::: "memory");       // pin LDS reads below the barrier
    // ---- S^T = K Q^T : 4 key m-tiles x 4 k-steps ----
    f32x4 st[4];
#pragma unroll
    for (int t = 0; t < 4; ++t) st[t] = (f32x4){0.f, 0.f, 0.f, 0.f};
    __builtin_amdgcn_s_setprio(1);
#pragma unroll
    for (int ks = 0; ks < 4; ++ks) {
#pragma unroll
      for (int t = 0; t < 4; ++t) {
        bf16x8 ak = *(bf16x8*)&Ks[(t * 16 + l16) * 128 + (((ks * 4 + quad) ^ l16) << 3)];
        st[t] = __builtin_amdgcn_mfma_f32_16x16x32_bf16(ak, aq[ks], st[t], 0, 0, 0);
      }
    }
    __builtin_amdgcn_s_setprio(0);
    // ---- online softmax (scale pre-folded into Q) ----
    {
      const int q = q0 + wrow + l16;
      float rm = -1e30f;
      if (kt != qt) {
#pragma unroll
        for (int t = 0; t < 4; ++t)
#pragma unroll
          for (int r = 0; r < 4; ++r) rm = fmaxf(rm, st[t][r]);
      } else {
#pragma unroll
        for (int t = 0; t < 4; ++t)
#pragma unroll
          for (int r = 0; r < 4; ++r) {
            const int key = k0 + t * 16 + quad * 4 + r;
            if (key > q) st[t][r] = -1e30f;
            rm = fmaxf(rm, st[t][r]);
          }
      }
      rm = fmaxf(rm, __shfl_xor(rm, 16, 64));
      rm = fmaxf(rm, __shfl_xor(rm, 32, 64));
      const float mn = fmaxf(m, rm);
      float rs = 0.f;
#pragma unroll
      for (int t = 0; t < 4; ++t)
#pragma unroll
        for (int r = 0; r < 4; ++r) {
          st[t][r] = __expf(st[t][r] - mn);
          rs += st[t][r];
        }
      rs += __shfl_xor(rs, 16, 64);
      rs += __shfl_xor(rs, 32, 64);
      if (__any(rm > m)) {               // max grew: rescale O (exact: else
        const float alpha = __expf(m - mn);  // alpha==exp(0)==1, skip is
        lsum = lsum * alpha + rs;            // bit-identical)
        m = mn;
#pragma unroll
        for (int r = 0; r < 4; ++r) {
          const float ar = __shfl(alpha, quad * 4 + r, 64);
#pragma unroll
          for (int nt = 0; nt < 8; ++nt) o[nt][r] *= ar;
        }
      } else {
        lsum += rs;
      }
      const int prow = l16;
#pragma unroll
      for (int t = 0; t < 4; ++t) {
        bf16x4 pk = {(__bf16)st[t][0], (__bf16)st[t][1],
                     (__bf16)st[t][2], (__bf16)st[t][3]};
        const int wch = (t * 2 + (quad >> 1)) ^ (prow & 7);  // 16B-chunk swizzle
        *(bf16x4*)(Pw + prow * 128 + wch * 16 + (quad & 1) * 8) = pk;
      }
    }
    // ---- O += P V : per-wave P (no barrier) ----
    __builtin_amdgcn_s_setprio(1);
#pragma unroll
    for (int ks = 0; ks < 2; ++ks) {
      const int rch = ((ks * 4 + quad) ^ (l16 & 7)) << 4;   // swizzled 16B chunk
      bf16x8 pa = *(bf16x8*)(Pw + l16 * 128 + rch);
#pragma unroll
      for (int nt = 0; nt < 8; ++nt) {
        bf16x8 bv = *(bf16x8*)&Vs[(nt * 16 + l16) * 64 + (((ks * 4 + quad) ^ (l16 & 7)) << 3)];
        o[nt] = __builtin_amdgcn_mfma_f32_16x16x32_bf16(pa, bv, o[nt], 0, 0, 0);
      }
    }
    __builtin_amdgcn_s_setprio(0);
    // ---- end-of-tile: own LDS reads done, then free buf(kt^1) ----
    asm volatile("s_waitcnt lgkmcnt(0)" ::: "memory");
    __builtin_amdgcn_s_barrier();
    asm volatile("" ::: "memory");
  }
  // ---- epilogue: fused differential combine (loop-end barrier synced all) ----
  const float linv = 1.0f / lsum;
  if (w >= 4) {     // q-head 2hk+1: publish inv-scaled O
#pragma unroll
    for (int r = 0; r < 4; ++r) {
      const float inv = __shfl(linv, quad * 4 + r, 64);
      const int rr = wrow + quad * 4 + r;
#pragma unroll
      for (int nt = 0; nt < 8; ++nt)
        Ex[rr][nt * 16 + l16] = o[nt][r] * inv;
    }
  }
  __syncthreads();
  if (w < 4) {      // q-head 2hk: combine and write y
#pragma unroll
    for (int r = 0; r < 4; ++r) {
      const float inv = __shfl(linv, quad * 4 + r, 64);
      const int rr = wrow + quad * 4 + r;
      const int l = q0 + rr;
      const float lm = lam[l * 16 + hk];
      __bf16* dst = y + (size_t)l * 2048 + hk * 128;
#pragma unroll
      for (int nt = 0; nt < 8; ++nt) {
        const float v1 = o[nt][r] * inv;
        dst[nt * 16 + l16] = (__bf16)(v1 - lm * Ex[rr][nt * 16 + l16]);
      }
    }
  }
}

extern "C" void kernel_launch(void* const* d_in, const int* in_sizes, int n_in,
                              void* d_out, int out_size, void* d_ws, size_t ws_size,
                              hipStream_t stream) {
  const float* x     = (const float*)d_in[0];
  const float* W_DKV = (const float*)d_in[1];
  const float* W_UK  = (const float*)d_in[2];
  const float* W_UV  = (const float*)d_in[3];
  const float* W_DQ  = (const float*)d_in[4];
  const float* W_UQ  = (const float*)d_in[5];
  const float* W_lam = (const float*)d_in[6];
  const float* b_lam = (const float*)d_in[7];
  const float* W_out = (const float*)d_in[8];
  float* out = (float*)d_out;

  char* ws = (char*)d_ws;
  #define MB(n) ((size_t)(n) << 20)
  __bf16* x_bf   = (__bf16*)(ws + MB(0));    //  8 MB (2048x2048)
  __bf16* Wt_DKV = (__bf16*)(ws + MB(8));    //  2 MB (512x2048)
  __bf16* Wt_DQ  = (__bf16*)(ws + MB(10));   //  4 MB (1024x2048)
  __bf16* c_kv   = (__bf16*)(ws + MB(14));   //  2 MB (2048x512)
  __bf16* c_q    = (__bf16*)(ws + MB(16));   //  4 MB (2048x1024)
  __bf16* Wt_UK  = (__bf16*)(ws + MB(20));   //  2 MB (2048x512)
  __bf16* Wt_UV  = (__bf16*)(ws + MB(22));   //  2 MB (2048x512)
  __bf16* Wt_UQ  = (__bf16*)(ws + MB(24));   //  8 MB (4096x1024)
  __bf16* k_bf   = (__bf16*)(ws + MB(32));   //  8 MB (2048x2048) roped K
  __bf16* y_bf   = (__bf16*)(ws + MB(40));   //  8 MB (2048x2048)
  __bf16* q_bf   = (__bf16*)(ws + MB(48));   // 16 MB (2048x4096) un-roped
  __bf16* v_t    = (__bf16*)(ws + MB(64));   //  8 MB (2048x2048) V^T
  float*  lam    = (float*)(ws + MB(88));    // 128 KB
  float*  cosT   = (float*)(ws + MB(89));    //  1 MB
  float*  sinT   = (float*)(ws + MB(90));    //  1 MB
  __bf16* WlT    = (__bf16*)(ws + MB(91));   // 64 KB (16x2048)
  __bf16* Wt_out = (__bf16*)(ws + MB(92));   //  8 MB (2048x2048)  (total 100 MB)

  // one prep launch: 6 weight transposes + x cast + rope tables + W_lam^T
  prep_all<<<18560, 256, 0, stream>>>(W_DKV, W_DQ, W_UK, W_UV, W_UQ, W_out,
                                      x, W_lam,
                                      Wt_DKV, Wt_DQ, Wt_UK, Wt_UV, Wt_UQ, Wt_out,
                                      x_bf, WlT, cosT, sinT);
  // down-projections (BM=64 BK=64) + lam, one launch (13x32 grid)
  down_lam<<<dim3(13, 32), 256, 0, stream>>>(x_bf, Wt_DKV, Wt_DQ, c_kv, c_q,
                                             WlT, b_lam, lam);
  // up-projections with fused epilogues: UK->roped k_bf, UV->v_t (transposed),
  // UQ->q_bf.  Replaces ropek_transv + k/v round trips.
  up_fused3<<<dim3(64, 16), 256, 0, stream>>>(c_kv, Wt_UK, Wt_UV, c_q, Wt_UQ,
                                              k_bf, v_t, q_bf, cosT, sinT);
  // flash attention: 8-wave blocks, strict-LPT qt order -> y_bf
  attn_kernel3<<<512, 512, 0, stream>>>(q_bf, k_bf, v_t, cosT, sinT, lam, y_bf);
  // output projection, BM=64 BK=64 (512 blocks = 2/CU)
  gemm_mfma<64, 2, false><<<dim3(16, 32), 256, 0, stream>>>(y_bf, Wt_out, out, 2048, 2048, 2048);
}

// Round 9
// 300.508 us; speedup vs baseline: 1.0336x; 1.0336x over previous
//
#include <hip/hip_runtime.h>
#include <cstdint>
#include <cstddef>

typedef __bf16 bf16x8 __attribute__((ext_vector_type(8)));
typedef __bf16 bf16x4 __attribute__((ext_vector_type(4)));
typedef float f32x4 __attribute__((ext_vector_type(4)));

// ---------------------------------------------------------------------------
// Problem constants (B=1): D=2048, NH=16, DH=128, DC=512, DCQ=1024, L=2048
// ---------------------------------------------------------------------------

template <int N> __device__ __forceinline__ void waitcnt_vm() {
  if constexpr (N == 3)      asm volatile("s_waitcnt vmcnt(3)" ::: "memory");
  else if constexpr (N == 4) asm volatile("s_waitcnt vmcnt(4)" ::: "memory");
  else if constexpr (N == 6) asm volatile("s_waitcnt vmcnt(6)" ::: "memory");
  else if constexpr (N == 8) asm volatile("s_waitcnt vmcnt(8)" ::: "memory");
  else                       asm volatile("s_waitcnt vmcnt(0)" ::: "memory");
}

// ---------------------------------------------------------------------------
// MFMA GEMM core: acc(BMx128) += A(M,K) @ Bt(N,K)^T tile.  A,Bt row-major
// bf16.  BK = 32*NKS, 4 waves, double-buffered LDS + counted-vmcnt pipeline.
// On return: all waves have passed the trailing barrier (LDS reusable).
//  BM=128: waves 2x2 over (128,128), wave 64x64 (acc 4x4).
//  BM=64:  waves 2x2 over (64,128),  wave 32x64 (acc 2x4).
// ---------------------------------------------------------------------------
template <int BM, int NKS>
__device__ __forceinline__ void gemm_core(const __bf16* __restrict__ A,
                                          const __bf16* __restrict__ Bt,
                                          int K, int bm, int bn,
                                          __bf16* As, __bf16* Bs,
                                          f32x4 (*acc)[4]) {
  const int tid = threadIdx.x;
  const int w = tid >> 6;
  const int lane = tid & 63;
  const int quad = lane >> 4;
  const int l16 = lane & 15;
  constexpr int WM = (BM == 128) ? 64 : 32;   // wave M extent
  constexpr int MI = WM / 16;                 // acc rows (4 or 2)
  constexpr int NL = NKS * (BM / 64 + 2);     // loads/wave per stage
  const int wm = (w & 1) * WM;
  const int wn = (w >> 1) * 64;
  const int srow = lane >> 2;
  const int sseg = (lane & 3) * 8;

  // stage one BK-wide K-slice into LDS buffer `buf` (async, NL loads/wave)
  auto stage = [&](int k0, int buf) {
#pragma unroll
    for (int ks = 0; ks < NKS; ++ks) {
#pragma unroll
      for (int g = 0; g < BM / 64; ++g) {     // A: BM rows
        const int grp = w + g * 4;
        const __bf16* ga = A + (size_t)(bm + grp * 16 + srow) * K + k0 + ks * 32 + sseg;
        __builtin_amdgcn_global_load_lds(
            (const __attribute__((address_space(1))) void*)ga,
            (__attribute__((address_space(3))) void*)&As[(buf * NKS + ks) * (BM * 32) + grp * 512],
            16, 0, 0);
      }
#pragma unroll
      for (int g = 0; g < 2; ++g) {           // B: always 128 rows
        const int grp = w + g * 4;
        const __bf16* gb = Bt + (size_t)(bn + grp * 16 + srow) * K + k0 + ks * 32 + sseg;
        __builtin_amdgcn_global_load_lds(
            (const __attribute__((address_space(1))) void*)gb,
            (__attribute__((address_space(3))) void*)&Bs[(buf * NKS + ks) * 4096 + grp * 512],
            16, 0, 0);
      }
    }
  };

#pragma unroll
  for (int i = 0; i < MI; ++i)
#pragma unroll
    for (int j = 0; j < 4; ++j) acc[i][j] = (f32x4){0.f, 0.f, 0.f, 0.f};

  // Drain any prologue VMEM so vmcnt counts only staging traffic.
  asm volatile("s_waitcnt vmcnt(0)" ::: "memory");
  stage(0, 0);

  const int NIT = K / (32 * NKS);
  for (int it = 0; it < NIT; ++it) {
    const int cur = it & 1;
    if (it + 1 < NIT) {
      stage((it + 1) * 32 * NKS, cur ^ 1);
      waitcnt_vm<NL>();                // cur's NL loads done; next's in flight
    } else {
      waitcnt_vm<0>();
    }
    __builtin_amdgcn_s_barrier();      // all waves' cur tiles staged
    asm volatile("" ::: "memory");     // pin LDS reads below the barrier
    const __bf16* Ab = &As[cur * NKS * (BM * 32)];
    const __bf16* Bb = &Bs[cur * NKS * 4096];
#pragma unroll
    for (int ks = 0; ks < NKS; ++ks) {
      bf16x8 af[MI], bfr[4];
#pragma unroll
      for (int i = 0; i < MI; ++i)
        af[i] = *(const bf16x8*)&Ab[ks * (BM * 32) + (wm + i * 16 + l16) * 32 + quad * 8];
#pragma unroll
      for (int j = 0; j < 4; ++j)
        bfr[j] = *(const bf16x8*)&Bb[ks * 4096 + (wn + j * 16 + l16) * 32 + quad * 8];
#pragma unroll
      for (int i = 0; i < MI; ++i)
#pragma unroll
        for (int j = 0; j < 4; ++j)
          acc[i][j] = __builtin_amdgcn_mfma_f32_16x16x32_bf16(af[i], bfr[j],
                                                              acc[i][j], 0, 0, 0);
    }
    // own LDS reads done, then free buf(cur) for stage(it+2)
    asm volatile("s_waitcnt lgkmcnt(0)" ::: "memory");
    __builtin_amdgcn_s_barrier();
    asm volatile("" ::: "memory");
  }
}

// plain epilogue: store acc to C (bf16 or f32), row-major ldc = N
template <int BM, int NKS, bool BF16OUT>
__device__ __forceinline__ void gemm_body(const __bf16* __restrict__ A,
                                          const __bf16* __restrict__ Bt,
                                          void* __restrict__ Cv,
                                          int N, int K, int bm, int bn,
                                          __bf16* As, __bf16* Bs) {
  constexpr int MI = (BM == 128) ? 4 : 2;
  constexpr int WM = (BM == 128) ? 64 : 32;
  f32x4 acc[MI][4];
  gemm_core<BM, NKS>(A, Bt, K, bm, bn, As, Bs, acc);
  const int tid = threadIdx.x;
  const int w = tid >> 6, lane = tid & 63, quad = lane >> 4, l16 = lane & 15;
  const int wm = (w & 1) * WM, wn = (w >> 1) * 64;
#pragma unroll
  for (int i = 0; i < MI; ++i)
#pragma unroll
    for (int j = 0; j < 4; ++j)
#pragma unroll
      for (int r = 0; r < 4; ++r) {
        const int row = bm + wm + i * 16 + quad * 4 + r;
        const int col = bn + wn + j * 16 + l16;
        if constexpr (BF16OUT)
          ((__bf16*)Cv)[(size_t)row * N + col] = (__bf16)acc[i][j][r];
        else
          ((float*)Cv)[(size_t)row * N + col] = acc[i][j][r];
      }
}

template <int BM, int NKS, bool BF16OUT>
__global__ __launch_bounds__(256) void gemm_mfma(const __bf16* __restrict__ A,
                                                 const __bf16* __restrict__ Bt,
                                                 void* __restrict__ Cv,
                                                 int M, int N, int K) {
  __shared__ __bf16 As[2 * BM * 32 * NKS];
  __shared__ __bf16 Bs[2 * 128 * 32 * NKS];
  gemm_body<BM, NKS, BF16OUT>(A, Bt, Cv, N, K, blockIdx.y * BM, blockIdx.x * 128, As, Bs);
}

// ---------------------------------------------------------------------------
// down_lam: down-projections (DKV 4 col-tiles + DQ 8 col-tiles, BM=64 BK=64)
// + lam (sigmoid(x.W_lam+b), MFMA N=16) fused in one launch.
// Grid dim3(13, 32): bx<4 DKV, bx<12 DQ, bx==12 lam rows by*64..+63.
// ---------------------------------------------------------------------------
__global__ __launch_bounds__(256) void down_lam(
    const __bf16* __restrict__ x_bf, const __bf16* __restrict__ WtDKV,
    const __bf16* __restrict__ WtDQ, __bf16* __restrict__ c_kv,
    __bf16* __restrict__ c_q, const __bf16* __restrict__ WlT,
    const float* __restrict__ b_lam, float* __restrict__ lam) {
  __shared__ __bf16 As[2 * 64 * 32 * 2];     // 16 KB
  __shared__ __bf16 Bs[2 * 128 * 32 * 2];    // 32 KB
  const int bx = blockIdx.x;
  const int tid = threadIdx.x;
  if (bx == 12) {  // lam: rows by*64..+63 (w picks 16-row group)
    const int w = tid >> 6, lane = tid & 63, quad = lane >> 4, l16 = lane & 15;
    const int m0 = (blockIdx.y * 4 + w) * 16;
    const __bf16* xrow = x_bf + (size_t)(m0 + l16) * 2048 + quad * 8;
    const __bf16* wrow = WlT + (size_t)l16 * 2048 + quad * 8;
    f32x4 acc[4];
#pragma unroll
    for (int u = 0; u < 4; ++u) acc[u] = (f32x4){0.f, 0.f, 0.f, 0.f};
    for (int k0 = 0; k0 < 2048; k0 += 128) {
#pragma unroll
      for (int u = 0; u < 4; ++u) {
        bf16x8 a = *(const bf16x8*)&xrow[k0 + u * 32];
        bf16x8 b = *(const bf16x8*)&wrow[k0 + u * 32];
        acc[u] = __builtin_amdgcn_mfma_f32_16x16x32_bf16(a, b, acc[u], 0, 0, 0);
      }
    }
    const float bl = b_lam[l16];
#pragma unroll
    for (int r = 0; r < 4; ++r) {
      const float v = acc[0][r] + acc[1][r] + acc[2][r] + acc[3][r] + bl;
      lam[(size_t)(m0 + quad * 4 + r) * 16 + l16] = 1.0f / (1.0f + __expf(-v));
    }
    return;
  }
  if (bx < 4)
    gemm_body<64, 2, true>(x_bf, WtDKV, (void*)c_kv, 512, 2048,
                           blockIdx.y * 64, bx * 128, As, Bs);
  else
    gemm_body<64, 2, true>(x_bf, WtDQ, (void*)c_q, 1024, 2048,
                           blockIdx.y * 64, (bx - 4) * 128, As, Bs);
}

// ---------------------------------------------------------------------------
// up_fused3: up-projections UK/UV/UQ (BM=128 BK=32) with fused epilogues.
//  UK (bx<16):  K-RoPE applied in-epilogue (pairs d<->d^64 exchanged via a
//               32 KB LDS bf16 stash — bit-identical to the old separate
//               rope pass, which also roped bf16-rounded values).
//  UV (bx<32):  V written directly TRANSPOSED to v_t[d][l] (acc's 4
//               consecutive rows = 8 B contiguous in transposed layout).
//  UQ (else):   plain bf16 store to q_bf (roped later in attn, unchanged).
// Grid dim3(64, 16).
// ---------------------------------------------------------------------------
__global__ __launch_bounds__(256) void up_fused3(
    const __bf16* __restrict__ c_kv, const __bf16* __restrict__ WtUK,
    const __bf16* __restrict__ WtUV, const __bf16* __restrict__ c_q,
    const __bf16* __restrict__ WtUQ, __bf16* __restrict__ k_bf,
    __bf16* __restrict__ v_t, __bf16* __restrict__ q_bf,
    const float* __restrict__ cosT, const float* __restrict__ sinT) {
  __shared__ __align__(16) char usm[32768];
  __bf16* As = (__bf16*)usm;             // 16 KB (2 buf x 128x32)
  __bf16* Bs = (__bf16*)(usm + 16384);   // 16 KB
  const int bx = blockIdx.x;
  const int bm = blockIdx.y * 128;
  const int tid = threadIdx.x;
  const int w = tid >> 6, lane = tid & 63, quad = lane >> 4, l16 = lane & 15;
  const int wm = (w & 1) * 64, wn = (w >> 1) * 64;
  f32x4 acc[4][4];
  if (bx < 16) {          // ---- UK -> roped K ----
    const int bn = bx * 128;   // head-aligned (128-wide heads)
    gemm_core<128, 1>(c_kv, WtUK, 512, bm, bn, As, Bs, acc);
    // gemm_core's trailing barrier freed usm; stash bf16 tile for pairs
    __bf16 (*Kt)[128] = (__bf16(*)[128])usm;
#pragma unroll
    for (int i = 0; i < 4; ++i)
#pragma unroll
      for (int j = 0; j < 4; ++j)
#pragma unroll
        for (int r = 0; r < 4; ++r)
          Kt[wm + i * 16 + quad * 4 + r][wn + j * 16 + l16] = (__bf16)acc[i][j][r];
    __syncthreads();
#pragma unroll
    for (int j = 0; j < 4; ++j) {
      const int d = wn + j * 16 + l16;
      const float sgn = (d < 64) ? -1.f : 1.f;
#pragma unroll
      for (int i = 0; i < 4; ++i)
#pragma unroll
        for (int r = 0; r < 4; ++r) {
          const int lr = wm + i * 16 + quad * 4 + r;
          const int l = bm + lr;
          const float v = (float)Kt[lr][d];        // == bf16(acc), as before
          const float pr = (float)Kt[lr][d ^ 64];
          const float ov = v * cosT[l * 128 + d] + sgn * pr * sinT[l * 128 + d];
          k_bf[(size_t)l * 2048 + bn + d] = (__bf16)ov;
        }
    }
  } else if (bx < 32) {   // ---- UV -> transposed V ----
    const int bn = (bx - 16) * 128;
    gemm_core<128, 1>(c_kv, WtUV, 512, bm, bn, As, Bs, acc);
#pragma unroll
    for (int i = 0; i < 4; ++i)
#pragma unroll
      for (int j = 0; j < 4; ++j) {
        const int d = bn + wn + j * 16 + l16;       // global dim = v_t row
        const int l = bm + wm + i * 16 + quad * 4;  // 4 consecutive l
        bf16x4 pk = {(__bf16)acc[i][j][0], (__bf16)acc[i][j][1],
                     (__bf16)acc[i][j][2], (__bf16)acc[i][j][3]};
        *(bf16x4*)&v_t[(size_t)d * 2048 + l] = pk;
      }
  } else {                // ---- UQ -> plain q_bf ----
    const int bn = (bx - 32) * 128;
    gemm_core<128, 1>(c_q, WtUQ, 1024, bm, bn, As, Bs, acc);
#pragma unroll
    for (int i = 0; i < 4; ++i)
#pragma unroll
      for (int j = 0; j < 4; ++j)
#pragma unroll
        for (int r = 0; r < 4; ++r) {
          const int row = bm + wm + i * 16 + quad * 4 + r;
          const int col = bn + wn + j * 16 + l16;
          q_bf[(size_t)row * 4096 + col] = (__bf16)acc[i][j][r];
        }
  }
}

// ---------------------------------------------------------------------------
// prep_all: weight transposes except W_out (moved to attn-launch rider),
// x cast, rope tables, W_lam transpose — one launch.  Grid 14464.
// ---------------------------------------------------------------------------
__global__ __launch_bounds__(256) void prep_all(
    const float* __restrict__ W_DKV, const float* __restrict__ W_DQ,
    const float* __restrict__ W_UK,  const float* __restrict__ W_UV,
    const float* __restrict__ W_UQ,
    const float* __restrict__ x,     const float* __restrict__ W_lam,
    __bf16* __restrict__ tDKV, __bf16* __restrict__ tDQ,
    __bf16* __restrict__ tUK,  __bf16* __restrict__ tUV,
    __bf16* __restrict__ tUQ,
    __bf16* __restrict__ x_bf, __bf16* __restrict__ WlT,
    float* __restrict__ cosT, float* __restrict__ sinT) {
  __shared__ float T[32][36];
  int t = blockIdx.x;
  const int tid = threadIdx.x;
  if (t < 9216) {
    const float* src; __bf16* dst; int K, N, kx, ny;
    if (t < 1024)      {            src = W_DKV; dst = tDKV; K = 2048; N = 512;  kx = t & 63; ny = t >> 6; }
    else if (t < 3072) { t -= 1024; src = W_DQ;  dst = tDQ;  K = 2048; N = 1024; kx = t & 63; ny = t >> 6; }
    else if (t < 4096) { t -= 3072; src = W_UK;  dst = tUK;  K = 512;  N = 2048; kx = t & 15; ny = t >> 4; }
    else if (t < 5120) { t -= 4096; src = W_UV;  dst = tUV;  K = 512;  N = 2048; kx = t & 15; ny = t >> 4; }
    else               { t -= 5120; src = W_UQ;  dst = tUQ;  K = 1024; N = 4096; kx = t & 31; ny = t >> 5; }
    const int k0 = kx * 32;
    const int n0 = ny * 32;
    const int r = tid >> 3;
    const int c = (tid & 7) * 4;
    *(float4*)&T[r][c] = *(const float4*)&src[(size_t)(k0 + r) * N + n0 + c];
    __syncthreads();
    bf16x4 o = {(__bf16)T[c + 0][r], (__bf16)T[c + 1][r],
                (__bf16)T[c + 2][r], (__bf16)T[c + 3][r]};
    *(bf16x4*)&dst[(size_t)(n0 + r) * K + k0 + c] = o;
    return;
  }
  t -= 9216;
  if (t < 4096) {  // x cast: 4096 blocks x 1024 floats
    const int i = t * 256 + tid;
    float4 v = *(const float4*)&x[(size_t)i * 4];
    bf16x4 o = {(__bf16)v.x, (__bf16)v.y, (__bf16)v.z, (__bf16)v.w};
    *(bf16x4*)&x_bf[(size_t)i * 4] = o;
    return;
  }
  t -= 4096;
  if (t < 1024) {  // rope tables: 2 rows per block
    const int l = t * 2 + (tid >> 7);
    const int d = tid & 127;
    const int j = d & 63;
    const float inv = exp2f(-(float)j * 0.2076205059304601f);  // log2(1e4)/64
    const float ang = (float)l * inv;
    cosT[l * 128 + d] = cosf(ang);
    sinT[l * 128 + d] = sinf(ang);
    return;
  }
  t -= 1024;
  {  // W_lam (2048,16) -> WlT (16,2048) bf16: 128 blocks
    const int i = t * 256 + tid;
    const int k = i >> 4, n = i & 15;
    WlT[(size_t)n * 2048 + k] = (__bf16)W_lam[i];
  }
}

// ---------------------------------------------------------------------------
// MFMA flash attention, 512-thread blocks (8 waves), double-buffered K/V,
// counted-vmcnt pipeline + setprio.  Wave w (0..7) owns 16 q-rows of head
// (w>>2) — 16 waves/CU = 4/SIMD.  R5 PAIRING restored (R7 post-mortem: with
// 512 blocks at 2/CU, bx and bx+256 co-reside; qt pairs must sum to 31 —
// hv ? ii>>4 : 31-(ii>>4)).  Exact defer-rescale (alpha==1 skip).
//  bx < 512: attn.  bx >= 512: W_out transpose rider (2 tiles/block) —
//  runs in attn's LPT tail, hiding W_out's HBM traffic under attn compute;
//  launch boundary orders it before the out-projection.
//  LDS = 81920 B (2 blocks/CU): buf0/buf1 K 64x128 + V^T 128x64 + per-wave P.
// ---------------------------------------------------------------------------
__global__ __launch_bounds__(512, 2) void attn_kernel3(
    const __bf16* __restrict__ Qb, const __bf16* __restrict__ Kb,
    const __bf16* __restrict__ Vt, const float* __restrict__ cosT,
    const float* __restrict__ sinT, const float* __restrict__ lam,
    __bf16* __restrict__ y, const float* __restrict__ W_out,
    __bf16* __restrict__ Wt_out) {
  __shared__ __align__(16) char smem[81920];
  float (*Ex)[132] = (float(*)[132])smem;              // epilogue union (33.8 KB)

  const int bx = blockIdx.x;
  const int tid = threadIdx.x;
  if (bx >= 512) {  // ---- W_out transpose rider: 2 32x32 tiles per block ----
    const int t = (bx - 512) * 2 + (tid >> 8);
    const int st = tid & 255;
    float (*T)[36] = (float(*)[36])(smem + (tid >> 8) * 4608);
    const int k0 = (t & 63) * 32;
    const int n0 = (t >> 6) * 32;
    const int r = st >> 3;
    const int c = (st & 7) * 4;
    *(float4*)&T[r][c] = *(const float4*)&W_out[(size_t)(k0 + r) * 2048 + n0 + c];
    __syncthreads();
    bf16x4 o = {(__bf16)T[c + 0][r], (__bf16)T[c + 1][r],
                (__bf16)T[c + 2][r], (__bf16)T[c + 3][r]};
    *(bf16x4*)&Wt_out[(size_t)(n0 + r) * 2048 + k0 + c] = o;
    return;
  }
  const int hv = bx >> 8;
  const int ii = bx & 255;
  const int qt = hv ? (ii >> 4) : 31 - (ii >> 4);  // pairs (31-k, k) per CU
  const int hk = ii & 15;
  const int q0 = qt * 64;
  const int w = tid >> 6, lane = tid & 63, quad = lane >> 4, l16 = lane & 15;
  const int wrow = (w & 3) * 16;              // wave's 16-row group
  const int qoff = (2 * hk + (w >> 2)) * 128; // wave's q-head
  const int kvoff = hk * 128;
  const float qscale = 0.08838834764831845f;  // 1/sqrt(128), folded into Q
  char* Pw = smem + 65536 + w * 2048;         // 16 rows x 128 B per wave

  // ---- Q fragment + RoPE + scale in-register (one 16-row subtile) ----
  bf16x8 aq[4];
  {
    const int l = q0 + wrow + l16;
    const size_t qbase = (size_t)l * 4096 + qoff + quad * 8;
    bf16x8 raw[4];
#pragma unroll
    for (int ks = 0; ks < 4; ++ks)
      raw[ks] = *(const bf16x8*)&Qb[qbase + ks * 32];
#pragma unroll
    for (int ks = 0; ks < 4; ++ks) {
      const float* cp = &cosT[l * 128 + ks * 32 + quad * 8];
      const float* sp = &sinT[l * 128 + ks * 32 + quad * 8];
#pragma unroll
      for (int j = 0; j < 8; ++j) {
        const float cv = cp[j];
        const float sv = sp[j];
        const float rot = (ks < 2) ? -(float)raw[ks + 2][j] : (float)raw[ks - 2][j];
        aq[ks][j] = (__bf16)(((float)raw[ks][j] * cv + rot * sv) * qscale);
      }
    }
  }

  // ---- staging helper: 4 global_load_lds per wave into chosen buffer ----
  auto stage = [&](int kt_, char* buf) {
    const int k0_ = kt_ * 64;
    __bf16* Ksb = (__bf16*)buf;
    __bf16* Vsb = (__bf16*)(buf + 16384);
#pragma unroll
    for (int d = 0; d < 2; ++d) {
      const int r0 = w * 8 + d * 4;              // 4 K-rows per DMA
      const int row = r0 + (lane >> 4);
      const int ck = (lane & 15) ^ (row & 15);
      const __bf16* ga = Kb + (size_t)(k0_ + row) * 2048 + kvoff + ck * 8;
      __builtin_amdgcn_global_load_lds(
          (const __attribute__((address_space(1))) void*)ga,
          (__attribute__((address_space(3))) void*)&Ksb[r0 * 128], 16, 0, 0);
      const int r0v = w * 16 + d * 8;            // 8 V-rows per DMA
      const int rowv = r0v + (lane >> 3);
      const int cv = (lane & 7) ^ (rowv & 7);
      const __bf16* gv = Vt + (size_t)(kvoff + rowv) * 2048 + k0_ + cv * 8;
      __builtin_amdgcn_global_load_lds(
          (const __attribute__((address_space(1))) void*)gv,
          (__attribute__((address_space(3))) void*)&Vsb[r0v * 64], 16, 0, 0);
    }
  };

  f32x4 o[8];
#pragma unroll
  for (int i = 0; i < 8; ++i) o[i] = (f32x4){0.f, 0.f, 0.f, 0.f};
  float m = -1e30f, lsum = 0.f;

  // Drain Q/rope loads so vmcnt counts only staging traffic, then prologue.
  asm volatile("s_waitcnt vmcnt(0)" ::: "memory");
  stage(0, smem);

  for (int kt = 0; kt <= qt; ++kt) {
    const int cur = kt & 1;
    __bf16* Ks = (__bf16*)(smem + cur * 32768);
    __bf16* Vs = (__bf16*)(smem + cur * 32768 + 16384);
    const int k0 = kt * 64;
    if (kt < qt) {
      stage(kt + 1, smem + (cur ^ 1) * 32768);
      asm volatile("s_waitcnt vmcnt(4)" ::: "memory");  // kt's 4 loads done
    } else {
      asm volatile("s_waitcnt vmcnt(0)" ::: "memory");
    }
    __builtin_amdgcn_s_barrier();        // all waves' kt tiles staged
    asm volatile("" ::: "memory");       // pin LDS reads below the barrier
    // ---- S^T = K Q^T : 4 key m-tiles x 4 k-steps ----
    f32x4 st[4];
#pragma unroll
    for (int t = 0; t < 4; ++t) st[t] = (f32x4){0.f, 0.f, 0.f, 0.f};
    __builtin_amdgcn_s_setprio(1);
#pragma unroll
    for (int ks = 0; ks < 4; ++ks) {
#pragma unroll
      for (int t = 0; t < 4; ++t) {
        bf16x8 ak = *(bf16x8*)&Ks[(t * 16 + l16) * 128 + (((ks * 4 + quad) ^ l16) << 3)];
        st[t] = __builtin_amdgcn_mfma_f32_16x16x32_bf16(ak, aq[ks], st[t], 0, 0, 0);
      }
    }
    __builtin_amdgcn_s_setprio(0);
    // ---- online softmax (scale pre-folded into Q) ----
    {
      const int q = q0 + wrow + l16;
      float rm = -1e30f;
      if (kt != qt) {
#pragma unroll
        for (int t = 0; t < 4; ++t)
#pragma unroll
          for (int r = 0; r < 4; ++r) rm = fmaxf(rm, st[t][r]);
      } else {
#pragma unroll
        for (int t = 0; t < 4; ++t)
#pragma unroll
          for (int r = 0; r < 4; ++r) {
            const int key = k0 + t * 16 + quad * 4 + r;
            if (key > q) st[t][r] = -1e30f;
            rm = fmaxf(rm, st[t][r]);
          }
      }
      rm = fmaxf(rm, __shfl_xor(rm, 16, 64));
      rm = fmaxf(rm, __shfl_xor(rm, 32, 64));
      const float mn = fmaxf(m, rm);
      float rs = 0.f;
#pragma unroll
      for (int t = 0; t < 4; ++t)
#pragma unroll
        for (int r = 0; r < 4; ++r) {
          st[t][r] = __expf(st[t][r] - mn);
          rs += st[t][r];
        }
      rs += __shfl_xor(rs, 16, 64);
      rs += __shfl_xor(rs, 32, 64);
      if (__any(rm > m)) {               // max grew: rescale O (exact: else
        const float alpha = __expf(m - mn);  // alpha==exp(0)==1, skip is
        lsum = lsum * alpha + rs;            // bit-identical)
        m = mn;
#pragma unroll
        for (int r = 0; r < 4; ++r) {
          const float ar = __shfl(alpha, quad * 4 + r, 64);
#pragma unroll
          for (int nt = 0; nt < 8; ++nt) o[nt][r] *= ar;
        }
      } else {
        lsum += rs;
      }
      const int prow = l16;
#pragma unroll
      for (int t = 0; t < 4; ++t) {
        bf16x4 pk = {(__bf16)st[t][0], (__bf16)st[t][1],
                     (__bf16)st[t][2], (__bf16)st[t][3]};
        const int wch = (t * 2 + (quad >> 1)) ^ (prow & 7);  // 16B-chunk swizzle
        *(bf16x4*)(Pw + prow * 128 + wch * 16 + (quad & 1) * 8) = pk;
      }
    }
    // ---- O += P V : per-wave P (no barrier) ----
    __builtin_amdgcn_s_setprio(1);
#pragma unroll
    for (int ks = 0; ks < 2; ++ks) {
      const int rch = ((ks * 4 + quad) ^ (l16 & 7)) << 4;   // swizzled 16B chunk
      bf16x8 pa = *(bf16x8*)(Pw + l16 * 128 + rch);
#pragma unroll
      for (int nt = 0; nt < 8; ++nt) {
        bf16x8 bv = *(bf16x8*)&Vs[(nt * 16 + l16) * 64 + (((ks * 4 + quad) ^ (l16 & 7)) << 3)];
        o[nt] = __builtin_amdgcn_mfma_f32_16x16x32_bf16(pa, bv, o[nt], 0, 0, 0);
      }
    }
    __builtin_amdgcn_s_setprio(0);
    // ---- end-of-tile: own LDS reads done, then free buf(kt^1) ----
    asm volatile("s_waitcnt lgkmcnt(0)" ::: "memory");
    __builtin_amdgcn_s_barrier();
    asm volatile("" ::: "memory");
  }
  // ---- epilogue: fused differential combine (loop-end barrier synced all) ----
  const float linv = 1.0f / lsum;
  if (w >= 4) {     // q-head 2hk+1: publish inv-scaled O
#pragma unroll
    for (int r = 0; r < 4; ++r) {
      const float inv = __shfl(linv, quad * 4 + r, 64);
      const int rr = wrow + quad * 4 + r;
#pragma unroll
      for (int nt = 0; nt < 8; ++nt)
        Ex[rr][nt * 16 + l16] = o[nt][r] * inv;
    }
  }
  __syncthreads();
  if (w < 4) {      // q-head 2hk: combine and write y
#pragma unroll
    for (int r = 0; r < 4; ++r) {
      const float inv = __shfl(linv, quad * 4 + r, 64);
      const int rr = wrow + quad * 4 + r;
      const int l = q0 + rr;
      const float lm = lam[l * 16 + hk];
      __bf16* dst = y + (size_t)l * 2048 + hk * 128;
#pragma unroll
      for (int nt = 0; nt < 8; ++nt) {
        const float v1 = o[nt][r] * inv;
        dst[nt * 16 + l16] = (__bf16)(v1 - lm * Ex[rr][nt * 16 + l16]);
      }
    }
  }
}

extern "C" void kernel_launch(void* const* d_in, const int* in_sizes, int n_in,
                              void* d_out, int out_size, void* d_ws, size_t ws_size,
                              hipStream_t stream) {
  const float* x     = (const float*)d_in[0];
  const float* W_DKV = (const float*)d_in[1];
  const float* W_UK  = (const float*)d_in[2];
  const float* W_UV  = (const float*)d_in[3];
  const float* W_DQ  = (const float*)d_in[4];
  const float* W_UQ  = (const float*)d_in[5];
  const float* W_lam = (const float*)d_in[6];
  const float* b_lam = (const float*)d_in[7];
  const float* W_out = (const float*)d_in[8];
  float* out = (float*)d_out;

  char* ws = (char*)d_ws;
  #define MB(n) ((size_t)(n) << 20)
  __bf16* x_bf   = (__bf16*)(ws + MB(0));    //  8 MB (2048x2048)
  __bf16* Wt_DKV = (__bf16*)(ws + MB(8));    //  2 MB (512x2048)
  __bf16* Wt_DQ  = (__bf16*)(ws + MB(10));   //  4 MB (1024x2048)
  __bf16* c_kv   = (__bf16*)(ws + MB(14));   //  2 MB (2048x512)
  __bf16* c_q    = (__bf16*)(ws + MB(16));   //  4 MB (2048x1024)
  __bf16* Wt_UK  = (__bf16*)(ws + MB(20));   //  2 MB (2048x512)
  __bf16* Wt_UV  = (__bf16*)(ws + MB(22));   //  2 MB (2048x512)
  __bf16* Wt_UQ  = (__bf16*)(ws + MB(24));   //  8 MB (4096x1024)
  __bf16* k_bf   = (__bf16*)(ws + MB(32));   //  8 MB (2048x2048) roped K
  __bf16* y_bf   = (__bf16*)(ws + MB(40));   //  8 MB (2048x2048)
  __bf16* q_bf   = (__bf16*)(ws + MB(48));   // 16 MB (2048x4096) un-roped
  __bf16* v_t    = (__bf16*)(ws + MB(64));   //  8 MB (2048x2048) V^T
  float*  lam    = (float*)(ws + MB(88));    // 128 KB
  float*  cosT   = (float*)(ws + MB(89));    //  1 MB
  float*  sinT   = (float*)(ws + MB(90));    //  1 MB
  __bf16* WlT    = (__bf16*)(ws + MB(91));   // 64 KB (16x2048)
  __bf16* Wt_out = (__bf16*)(ws + MB(92));   //  8 MB (2048x2048)  (total 100 MB)

  // prep launch (no W_out — that transpose rides the attn launch)
  prep_all<<<14464, 256, 0, stream>>>(W_DKV, W_DQ, W_UK, W_UV, W_UQ,
                                      x, W_lam,
                                      Wt_DKV, Wt_DQ, Wt_UK, Wt_UV, Wt_UQ,
                                      x_bf, WlT, cosT, sinT);
  // down-projections (BM=64 BK=64) + lam, one launch (13x32 grid)
  down_lam<<<dim3(13, 32), 256, 0, stream>>>(x_bf, Wt_DKV, Wt_DQ, c_kv, c_q,
                                             WlT, b_lam, lam);
  // up-projections with fused epilogues: UK->roped k_bf, UV->v_t (transposed),
  // UQ->q_bf.
  up_fused3<<<dim3(64, 16), 256, 0, stream>>>(c_kv, Wt_UK, Wt_UV, c_q, Wt_UQ,
                                              k_bf, v_t, q_bf, cosT, sinT);
  // flash attention (512 blocks, R5 pairing) + W_out-transpose rider (2048)
  attn_kernel3<<<2560, 512, 0, stream>>>(q_bf, k_bf, v_t, cosT, sinT, lam,
                                         y_bf, W_out, Wt_out);
  // output projection, BM=64 BK=64 (512 blocks = 2/CU)
  gemm_mfma<64, 2, false><<<dim3(16, 32), 256, 0, stream>>>(y_bf, Wt_out, out, 2048, 2048, 2048);
}

// Round 10
// 288.376 us; speedup vs baseline: 1.0770x; 1.0421x over previous
//
#include <hip/hip_runtime.h>
#include <cstdint>
#include <cstddef>

typedef __bf16 bf16x8 __attribute__((ext_vector_type(8)));
typedef __bf16 bf16x4 __attribute__((ext_vector_type(4)));
typedef float f32x4 __attribute__((ext_vector_type(4)));

// ---------------------------------------------------------------------------
// Problem constants (B=1): D=2048, NH=16, DH=128, DC=512, DCQ=1024, L=2048
// ---------------------------------------------------------------------------

template <int N> __device__ __forceinline__ void waitcnt_vm() {
  if constexpr (N == 3)      asm volatile("s_waitcnt vmcnt(3)" ::: "memory");
  else if constexpr (N == 4) asm volatile("s_waitcnt vmcnt(4)" ::: "memory");
  else if constexpr (N == 6) asm volatile("s_waitcnt vmcnt(6)" ::: "memory");
  else if constexpr (N == 8) asm volatile("s_waitcnt vmcnt(8)" ::: "memory");
  else                       asm volatile("s_waitcnt vmcnt(0)" ::: "memory");
}

// ---------------------------------------------------------------------------
// MFMA GEMM core: acc(BMx128) += A(M,K) @ Bt(N,K)^T tile.  A,Bt row-major
// bf16.  BK = 32*NKS, 4 waves, double-buffered LDS + counted-vmcnt pipeline.
// On return: all waves have passed the trailing barrier (LDS reusable).
//  BM=128: waves 2x2 over (128,128), wave 64x64 (acc 4x4).
//  BM=64:  waves 2x2 over (64,128),  wave 32x64 (acc 2x4).
// ---------------------------------------------------------------------------
template <int BM, int NKS>
__device__ __forceinline__ void gemm_core(const __bf16* __restrict__ A,
                                          const __bf16* __restrict__ Bt,
                                          int K, int bm, int bn,
                                          __bf16* As, __bf16* Bs,
                                          f32x4 (*acc)[4]) {
  const int tid = threadIdx.x;
  const int w = tid >> 6;
  const int lane = tid & 63;
  const int quad = lane >> 4;
  const int l16 = lane & 15;
  constexpr int WM = (BM == 128) ? 64 : 32;   // wave M extent
  constexpr int MI = WM / 16;                 // acc rows (4 or 2)
  constexpr int NL = NKS * (BM / 64 + 2);     // loads/wave per stage
  const int wm = (w & 1) * WM;
  const int wn = (w >> 1) * 64;
  const int srow = lane >> 2;
  const int sseg = (lane & 3) * 8;

  // stage one BK-wide K-slice into LDS buffer `buf` (async, NL loads/wave)
  auto stage = [&](int k0, int buf) {
#pragma unroll
    for (int ks = 0; ks < NKS; ++ks) {
#pragma unroll
      for (int g = 0; g < BM / 64; ++g) {     // A: BM rows
        const int grp = w + g * 4;
        const __bf16* ga = A + (size_t)(bm + grp * 16 + srow) * K + k0 + ks * 32 + sseg;
        __builtin_amdgcn_global_load_lds(
            (const __attribute__((address_space(1))) void*)ga,
            (__attribute__((address_space(3))) void*)&As[(buf * NKS + ks) * (BM * 32) + grp * 512],
            16, 0, 0);
      }
#pragma unroll
      for (int g = 0; g < 2; ++g) {           // B: always 128 rows
        const int grp = w + g * 4;
        const __bf16* gb = Bt + (size_t)(bn + grp * 16 + srow) * K + k0 + ks * 32 + sseg;
        __builtin_amdgcn_global_load_lds(
            (const __attribute__((address_space(1))) void*)gb,
            (__attribute__((address_space(3))) void*)&Bs[(buf * NKS + ks) * 4096 + grp * 512],
            16, 0, 0);
      }
    }
  };

#pragma unroll
  for (int i = 0; i < MI; ++i)
#pragma unroll
    for (int j = 0; j < 4; ++j) acc[i][j] = (f32x4){0.f, 0.f, 0.f, 0.f};

  // Drain any prologue VMEM so vmcnt counts only staging traffic.
  asm volatile("s_waitcnt vmcnt(0)" ::: "memory");
  stage(0, 0);

  const int NIT = K / (32 * NKS);
  for (int it = 0; it < NIT; ++it) {
    const int cur = it & 1;
    if (it + 1 < NIT) {
      stage((it + 1) * 32 * NKS, cur ^ 1);
      waitcnt_vm<NL>();                // cur's NL loads done; next's in flight
    } else {
      waitcnt_vm<0>();
    }
    __builtin_amdgcn_s_barrier();      // all waves' cur tiles staged
    asm volatile("" ::: "memory");     // pin LDS reads below the barrier
    const __bf16* Ab = &As[cur * NKS * (BM * 32)];
    const __bf16* Bb = &Bs[cur * NKS * 4096];
#pragma unroll
    for (int ks = 0; ks < NKS; ++ks) {
      bf16x8 af[MI], bfr[4];
#pragma unroll
      for (int i = 0; i < MI; ++i)
        af[i] = *(const bf16x8*)&Ab[ks * (BM * 32) + (wm + i * 16 + l16) * 32 + quad * 8];
#pragma unroll
      for (int j = 0; j < 4; ++j)
        bfr[j] = *(const bf16x8*)&Bb[ks * 4096 + (wn + j * 16 + l16) * 32 + quad * 8];
#pragma unroll
      for (int i = 0; i < MI; ++i)
#pragma unroll
        for (int j = 0; j < 4; ++j)
          acc[i][j] = __builtin_amdgcn_mfma_f32_16x16x32_bf16(af[i], bfr[j],
                                                              acc[i][j], 0, 0, 0);
    }
    // own LDS reads done, then free buf(cur) for stage(it+2)
    asm volatile("s_waitcnt lgkmcnt(0)" ::: "memory");
    __builtin_amdgcn_s_barrier();
    asm volatile("" ::: "memory");
  }
}

// plain epilogue: store acc to C (bf16 or f32), row-major ldc = N
template <int BM, int NKS, bool BF16OUT>
__device__ __forceinline__ void gemm_body(const __bf16* __restrict__ A,
                                          const __bf16* __restrict__ Bt,
                                          void* __restrict__ Cv,
                                          int N, int K, int bm, int bn,
                                          __bf16* As, __bf16* Bs) {
  constexpr int MI = (BM == 128) ? 4 : 2;
  constexpr int WM = (BM == 128) ? 64 : 32;
  f32x4 acc[MI][4];
  gemm_core<BM, NKS>(A, Bt, K, bm, bn, As, Bs, acc);
  const int tid = threadIdx.x;
  const int w = tid >> 6, lane = tid & 63, quad = lane >> 4, l16 = lane & 15;
  const int wm = (w & 1) * WM, wn = (w >> 1) * 64;
#pragma unroll
  for (int i = 0; i < MI; ++i)
#pragma unroll
    for (int j = 0; j < 4; ++j)
#pragma unroll
      for (int r = 0; r < 4; ++r) {
        const int row = bm + wm + i * 16 + quad * 4 + r;
        const int col = bn + wn + j * 16 + l16;
        if constexpr (BF16OUT)
          ((__bf16*)Cv)[(size_t)row * N + col] = (__bf16)acc[i][j][r];
        else
          ((float*)Cv)[(size_t)row * N + col] = acc[i][j][r];
      }
}

template <int BM, int NKS, bool BF16OUT>
__global__ __launch_bounds__(256) void gemm_mfma(const __bf16* __restrict__ A,
                                                 const __bf16* __restrict__ Bt,
                                                 void* __restrict__ Cv,
                                                 int M, int N, int K) {
  __shared__ __bf16 As[2 * BM * 32 * NKS];
  __shared__ __bf16 Bs[2 * 128 * 32 * NKS];
  gemm_body<BM, NKS, BF16OUT>(A, Bt, Cv, N, K, blockIdx.y * BM, blockIdx.x * 128, As, Bs);
}

// 32x32 fp32->bf16 transpose tile helper (T is >=32x36 float scratch)
__device__ __forceinline__ void transpose_tile(const float* __restrict__ src,
                                               __bf16* __restrict__ dst,
                                               int K, int N, int kx, int ny,
                                               float (*T)[36], int tid) {
  const int k0 = kx * 32;
  const int n0 = ny * 32;
  const int r = tid >> 3;
  const int c = (tid & 7) * 4;
  *(float4*)&T[r][c] = *(const float4*)&src[(size_t)(k0 + r) * N + n0 + c];
  __syncthreads();
  bf16x4 o = {(__bf16)T[c + 0][r], (__bf16)T[c + 1][r],
              (__bf16)T[c + 2][r], (__bf16)T[c + 3][r]};
  *(bf16x4*)&dst[(size_t)(n0 + r) * K + k0 + c] = o;
}

// ---------------------------------------------------------------------------
// down_lam: down-projections (DKV 4 col-tiles + DQ 8 col-tiles, BM=64 BK=64)
// + lam (sigmoid(x.W_lam+b), MFMA N=16), PLUS riders (R8 pattern extended):
// UK/UV/UQ weight transposes (6144 tiles) and rope tables (1024 blocks) —
// all consumed only by the NEXT launch (up_fused3), so the launch boundary
// orders them; riders backfill down_lam's idle CU slots and its LPT tail,
// hiding their HBM traffic under down's compute.
// 1D grid 7584: id<416 down/lam (bxl=id>>5, by=id&31); then 6144 transpose
// riders; then 1024 rope riders.
// ---------------------------------------------------------------------------
__global__ __launch_bounds__(256) void down_lam(
    const __bf16* __restrict__ x_bf, const __bf16* __restrict__ WtDKV,
    const __bf16* __restrict__ WtDQ, __bf16* __restrict__ c_kv,
    __bf16* __restrict__ c_q, const __bf16* __restrict__ WlT,
    const float* __restrict__ b_lam, float* __restrict__ lam,
    const float* __restrict__ W_UK, const float* __restrict__ W_UV,
    const float* __restrict__ W_UQ, __bf16* __restrict__ tUK,
    __bf16* __restrict__ tUV, __bf16* __restrict__ tUQ,
    float* __restrict__ cosT, float* __restrict__ sinT) {
  __shared__ __bf16 As[2 * 64 * 32 * 2];     // 16 KB
  __shared__ __bf16 Bs[2 * 128 * 32 * 2];    // 32 KB
  int id = blockIdx.x;
  const int tid = threadIdx.x;
  if (id < 416) {
    const int bxl = id >> 5, by = id & 31;
    if (bxl == 12) {  // lam: rows by*64..+63 (w picks 16-row group)
      const int w = tid >> 6, lane = tid & 63, quad = lane >> 4, l16 = lane & 15;
      const int m0 = (by * 4 + w) * 16;
      const __bf16* xrow = x_bf + (size_t)(m0 + l16) * 2048 + quad * 8;
      const __bf16* wrow = WlT + (size_t)l16 * 2048 + quad * 8;
      f32x4 acc[4];
#pragma unroll
      for (int u = 0; u < 4; ++u) acc[u] = (f32x4){0.f, 0.f, 0.f, 0.f};
      for (int k0 = 0; k0 < 2048; k0 += 128) {
#pragma unroll
        for (int u = 0; u < 4; ++u) {
          bf16x8 a = *(const bf16x8*)&xrow[k0 + u * 32];
          bf16x8 b = *(const bf16x8*)&wrow[k0 + u * 32];
          acc[u] = __builtin_amdgcn_mfma_f32_16x16x32_bf16(a, b, acc[u], 0, 0, 0);
        }
      }
      const float bl = b_lam[l16];
#pragma unroll
      for (int r = 0; r < 4; ++r) {
        const float v = acc[0][r] + acc[1][r] + acc[2][r] + acc[3][r] + bl;
        lam[(size_t)(m0 + quad * 4 + r) * 16 + l16] = 1.0f / (1.0f + __expf(-v));
      }
      return;
    }
    if (bxl < 4)
      gemm_body<64, 2, true>(x_bf, WtDKV, (void*)c_kv, 512, 2048,
                             by * 64, bxl * 128, As, Bs);
    else
      gemm_body<64, 2, true>(x_bf, WtDQ, (void*)c_q, 1024, 2048,
                             by * 64, (bxl - 4) * 128, As, Bs);
    return;
  }
  id -= 416;
  if (id < 6144) {  // ---- UK/UV/UQ transpose riders ----
    float (*T)[36] = (float(*)[36])As;
    if (id < 1024)
      transpose_tile(W_UK, tUK, 512, 2048, id & 15, id >> 4, T, tid);
    else if (id < 2048) {
      id -= 1024;
      transpose_tile(W_UV, tUV, 512, 2048, id & 15, id >> 4, T, tid);
    } else {
      id -= 2048;
      transpose_tile(W_UQ, tUQ, 1024, 4096, id & 31, id >> 5, T, tid);
    }
    return;
  }
  id -= 6144;
  {  // ---- rope tables rider: 2 rows per block ----
    const int l = id * 2 + (tid >> 7);
    const int d = tid & 127;
    const int j = d & 63;
    const float inv = exp2f(-(float)j * 0.2076205059304601f);  // log2(1e4)/64
    const float ang = (float)l * inv;
    cosT[l * 128 + d] = cosf(ang);
    sinT[l * 128 + d] = sinf(ang);
  }
}

// ---------------------------------------------------------------------------
// up_fused3: up-projections UK/UV/UQ (BM=128 BK=32) with fused epilogues.
//  UK (bx<16):  K-RoPE applied in-epilogue (pairs d<->d^64 via LDS stash).
//  UV (bx<32):  V written directly TRANSPOSED to v_t[d][l].
//  UQ (else):   plain bf16 store to q_bf (roped later in attn).
// Grid dim3(64, 16).
// ---------------------------------------------------------------------------
__global__ __launch_bounds__(256) void up_fused3(
    const __bf16* __restrict__ c_kv, const __bf16* __restrict__ WtUK,
    const __bf16* __restrict__ WtUV, const __bf16* __restrict__ c_q,
    const __bf16* __restrict__ WtUQ, __bf16* __restrict__ k_bf,
    __bf16* __restrict__ v_t, __bf16* __restrict__ q_bf,
    const float* __restrict__ cosT, const float* __restrict__ sinT) {
  __shared__ __align__(16) char usm[32768];
  __bf16* As = (__bf16*)usm;             // 16 KB (2 buf x 128x32)
  __bf16* Bs = (__bf16*)(usm + 16384);   // 16 KB
  const int bx = blockIdx.x;
  const int bm = blockIdx.y * 128;
  const int tid = threadIdx.x;
  const int w = tid >> 6, lane = tid & 63, quad = lane >> 4, l16 = lane & 15;
  const int wm = (w & 1) * 64, wn = (w >> 1) * 64;
  f32x4 acc[4][4];
  if (bx < 16) {          // ---- UK -> roped K ----
    const int bn = bx * 128;   // head-aligned (128-wide heads)
    gemm_core<128, 1>(c_kv, WtUK, 512, bm, bn, As, Bs, acc);
    // gemm_core's trailing barrier freed usm; stash bf16 tile for pairs
    __bf16 (*Kt)[128] = (__bf16(*)[128])usm;
#pragma unroll
    for (int i = 0; i < 4; ++i)
#pragma unroll
      for (int j = 0; j < 4; ++j)
#pragma unroll
        for (int r = 0; r < 4; ++r)
          Kt[wm + i * 16 + quad * 4 + r][wn + j * 16 + l16] = (__bf16)acc[i][j][r];
    __syncthreads();
#pragma unroll
    for (int j = 0; j < 4; ++j) {
      const int d = wn + j * 16 + l16;
      const float sgn = (d < 64) ? -1.f : 1.f;
#pragma unroll
      for (int i = 0; i < 4; ++i)
#pragma unroll
        for (int r = 0; r < 4; ++r) {
          const int lr = wm + i * 16 + quad * 4 + r;
          const int l = bm + lr;
          const float v = (float)Kt[lr][d];        // == bf16(acc), as before
          const float pr = (float)Kt[lr][d ^ 64];
          const float ov = v * cosT[l * 128 + d] + sgn * pr * sinT[l * 128 + d];
          k_bf[(size_t)l * 2048 + bn + d] = (__bf16)ov;
        }
    }
  } else if (bx < 32) {   // ---- UV -> transposed V ----
    const int bn = (bx - 16) * 128;
    gemm_core<128, 1>(c_kv, WtUV, 512, bm, bn, As, Bs, acc);
#pragma unroll
    for (int i = 0; i < 4; ++i)
#pragma unroll
      for (int j = 0; j < 4; ++j) {
        const int d = bn + wn + j * 16 + l16;       // global dim = v_t row
        const int l = bm + wm + i * 16 + quad * 4;  // 4 consecutive l
        bf16x4 pk = {(__bf16)acc[i][j][0], (__bf16)acc[i][j][1],
                     (__bf16)acc[i][j][2], (__bf16)acc[i][j][3]};
        *(bf16x4*)&v_t[(size_t)d * 2048 + l] = pk;
      }
  } else {                // ---- UQ -> plain q_bf ----
    const int bn = (bx - 32) * 128;
    gemm_core<128, 1>(c_q, WtUQ, 1024, bm, bn, As, Bs, acc);
#pragma unroll
    for (int i = 0; i < 4; ++i)
#pragma unroll
      for (int j = 0; j < 4; ++j)
#pragma unroll
        for (int r = 0; r < 4; ++r) {
          const int row = bm + wm + i * 16 + quad * 4 + r;
          const int col = bn + wn + j * 16 + l16;
          q_bf[(size_t)row * 4096 + col] = (__bf16)acc[i][j][r];
        }
  }
}

// ---------------------------------------------------------------------------
// prep_all: x cast + DKV/DQ weight transposes + W_lam transpose (only what
// down_lam needs; UK/UV/UQ transposes + rope tables ride down_lam's launch,
// W_out transpose rides attn's).  Grid 7296.
// ---------------------------------------------------------------------------
__global__ __launch_bounds__(256) void prep_all(
    const float* __restrict__ W_DKV, const float* __restrict__ W_DQ,
    const float* __restrict__ x,     const float* __restrict__ W_lam,
    __bf16* __restrict__ tDKV, __bf16* __restrict__ tDQ,
    __bf16* __restrict__ x_bf, __bf16* __restrict__ WlT) {
  __shared__ float T[32][36];
  int t = blockIdx.x;
  const int tid = threadIdx.x;
  if (t < 3072) {
    if (t < 1024)
      transpose_tile(W_DKV, tDKV, 2048, 512, t & 63, t >> 6, T, tid);
    else {
      t -= 1024;
      transpose_tile(W_DQ, tDQ, 2048, 1024, t & 63, t >> 6, T, tid);
    }
    return;
  }
  t -= 3072;
  if (t < 4096) {  // x cast: 4096 blocks x 1024 floats
    const int i = t * 256 + tid;
    float4 v = *(const float4*)&x[(size_t)i * 4];
    bf16x4 o = {(__bf16)v.x, (__bf16)v.y, (__bf16)v.z, (__bf16)v.w};
    *(bf16x4*)&x_bf[(size_t)i * 4] = o;
    return;
  }
  t -= 4096;
  {  // W_lam (2048,16) -> WlT (16,2048) bf16: 128 blocks
    const int i = t * 256 + tid;
    const int k = i >> 4, n = i & 15;
    WlT[(size_t)n * 2048 + k] = (__bf16)W_lam[i];
  }
}

// ---------------------------------------------------------------------------
// MFMA flash attention, 512-thread blocks (8 waves), double-buffered K/V,
// counted-vmcnt pipeline + setprio.  Wave w (0..7) owns 16 q-rows of head
// (w>>2) — 16 waves/CU = 4/SIMD.  R5 pairing (qt pairs sum to 31; bx and
// bx+256 co-reside at 2 blocks/CU).  Exact defer-rescale (alpha==1 skip).
//  bx < 512: attn.  bx >= 512: W_out transpose rider (2 tiles/block).
//  LDS = 81920 B (2 blocks/CU): buf0/buf1 K 64x128 + V^T 128x64 + per-wave P.
// ---------------------------------------------------------------------------
__global__ __launch_bounds__(512, 2) void attn_kernel3(
    const __bf16* __restrict__ Qb, const __bf16* __restrict__ Kb,
    const __bf16* __restrict__ Vt, const float* __restrict__ cosT,
    const float* __restrict__ sinT, const float* __restrict__ lam,
    __bf16* __restrict__ y, const float* __restrict__ W_out,
    __bf16* __restrict__ Wt_out) {
  __shared__ __align__(16) char smem[81920];
  float (*Ex)[132] = (float(*)[132])smem;              // epilogue union (33.8 KB)

  const int bx = blockIdx.x;
  const int tid = threadIdx.x;
  if (bx >= 512) {  // ---- W_out transpose rider: 2 32x32 tiles per block ----
    const int t = (bx - 512) * 2 + (tid >> 8);
    const int st = tid & 255;
    float (*T)[36] = (float(*)[36])(smem + (tid >> 8) * 4608);
    const int k0 = (t & 63) * 32;
    const int n0 = (t >> 6) * 32;
    const int r = st >> 3;
    const int c = (st & 7) * 4;
    *(float4*)&T[r][c] = *(const float4*)&W_out[(size_t)(k0 + r) * 2048 + n0 + c];
    __syncthreads();
    bf16x4 o = {(__bf16)T[c + 0][r], (__bf16)T[c + 1][r],
                (__bf16)T[c + 2][r], (__bf16)T[c + 3][r]};
    *(bf16x4*)&Wt_out[(size_t)(n0 + r) * 2048 + k0 + c] = o;
    return;
  }
  const int hv = bx >> 8;
  const int ii = bx & 255;
  const int qt = hv ? (ii >> 4) : 31 - (ii >> 4);  // pairs (31-k, k) per CU
  const int hk = ii & 15;
  const int q0 = qt * 64;
  const int w = tid >> 6, lane = tid & 63, quad = lane >> 4, l16 = lane & 15;
  const int wrow = (w & 3) * 16;              // wave's 16-row group
  const int qoff = (2 * hk + (w >> 2)) * 128; // wave's q-head
  const int kvoff = hk * 128;
  const float qscale = 0.08838834764831845f;  // 1/sqrt(128), folded into Q
  char* Pw = smem + 65536 + w * 2048;         // 16 rows x 128 B per wave

  // ---- Q fragment + RoPE + scale in-register (one 16-row subtile) ----
  bf16x8 aq[4];
  {
    const int l = q0 + wrow + l16;
    const size_t qbase = (size_t)l * 4096 + qoff + quad * 8;
    bf16x8 raw[4];
#pragma unroll
    for (int ks = 0; ks < 4; ++ks)
      raw[ks] = *(const bf16x8*)&Qb[qbase + ks * 32];
#pragma unroll
    for (int ks = 0; ks < 4; ++ks) {
      const float* cp = &cosT[l * 128 + ks * 32 + quad * 8];
      const float* sp = &sinT[l * 128 + ks * 32 + quad * 8];
#pragma unroll
      for (int j = 0; j < 8; ++j) {
        const float cv = cp[j];
        const float sv = sp[j];
        const float rot = (ks < 2) ? -(float)raw[ks + 2][j] : (float)raw[ks - 2][j];
        aq[ks][j] = (__bf16)(((float)raw[ks][j] * cv + rot * sv) * qscale);
      }
    }
  }

  // ---- staging helper: 4 global_load_lds per wave into chosen buffer ----
  auto stage = [&](int kt_, char* buf) {
    const int k0_ = kt_ * 64;
    __bf16* Ksb = (__bf16*)buf;
    __bf16* Vsb = (__bf16*)(buf + 16384);
#pragma unroll
    for (int d = 0; d < 2; ++d) {
      const int r0 = w * 8 + d * 4;              // 4 K-rows per DMA
      const int row = r0 + (lane >> 4);
      const int ck = (lane & 15) ^ (row & 15);
      const __bf16* ga = Kb + (size_t)(k0_ + row) * 2048 + kvoff + ck * 8;
      __builtin_amdgcn_global_load_lds(
          (const __attribute__((address_space(1))) void*)ga,
          (__attribute__((address_space(3))) void*)&Ksb[r0 * 128], 16, 0, 0);
      const int r0v = w * 16 + d * 8;            // 8 V-rows per DMA
      const int rowv = r0v + (lane >> 3);
      const int cv = (lane & 7) ^ (rowv & 7);
      const __bf16* gv = Vt + (size_t)(kvoff + rowv) * 2048 + k0_ + cv * 8;
      __builtin_amdgcn_global_load_lds(
          (const __attribute__((address_space(1))) void*)gv,
          (__attribute__((address_space(3))) void*)&Vsb[r0v * 64], 16, 0, 0);
    }
  };

  f32x4 o[8];
#pragma unroll
  for (int i = 0; i < 8; ++i) o[i] = (f32x4){0.f, 0.f, 0.f, 0.f};
  float m = -1e30f, lsum = 0.f;

  // Drain Q/rope loads so vmcnt counts only staging traffic, then prologue.
  asm volatile("s_waitcnt vmcnt(0)" ::: "memory");
  stage(0, smem);

  for (int kt = 0; kt <= qt; ++kt) {
    const int cur = kt & 1;
    __bf16* Ks = (__bf16*)(smem + cur * 32768);
    __bf16* Vs = (__bf16*)(smem + cur * 32768 + 16384);
    const int k0 = kt * 64;
    if (kt < qt) {
      stage(kt + 1, smem + (cur ^ 1) * 32768);
      asm volatile("s_waitcnt vmcnt(4)" ::: "memory");  // kt's 4 loads done
    } else {
      asm volatile("s_waitcnt vmcnt(0)" ::: "memory");
    }
    __builtin_amdgcn_s_barrier();        // all waves' kt tiles staged
    asm volatile("" ::: "memory");       // pin LDS reads below the barrier
    // ---- S^T = K Q^T : 4 key m-tiles x 4 k-steps ----
    f32x4 st[4];
#pragma unroll
    for (int t = 0; t < 4; ++t) st[t] = (f32x4){0.f, 0.f, 0.f, 0.f};
    __builtin_amdgcn_s_setprio(1);
#pragma unroll
    for (int ks = 0; ks < 4; ++ks) {
#pragma unroll
      for (int t = 0; t < 4; ++t) {
        bf16x8 ak = *(bf16x8*)&Ks[(t * 16 + l16) * 128 + (((ks * 4 + quad) ^ l16) << 3)];
        st[t] = __builtin_amdgcn_mfma_f32_16x16x32_bf16(ak, aq[ks], st[t], 0, 0, 0);
      }
    }
    __builtin_amdgcn_s_setprio(0);
    // ---- online softmax (scale pre-folded into Q) ----
    {
      const int q = q0 + wrow + l16;
      float rm = -1e30f;
      if (kt != qt) {
#pragma unroll
        for (int t = 0; t < 4; ++t)
#pragma unroll
          for (int r = 0; r < 4; ++r) rm = fmaxf(rm, st[t][r]);
      } else {
#pragma unroll
        for (int t = 0; t < 4; ++t)
#pragma unroll
          for (int r = 0; r < 4; ++r) {
            const int key = k0 + t * 16 + quad * 4 + r;
            if (key > q) st[t][r] = -1e30f;
            rm = fmaxf(rm, st[t][r]);
          }
      }
      rm = fmaxf(rm, __shfl_xor(rm, 16, 64));
      rm = fmaxf(rm, __shfl_xor(rm, 32, 64));
      const float mn = fmaxf(m, rm);
      float rs = 0.f;
#pragma unroll
      for (int t = 0; t < 4; ++t)
#pragma unroll
        for (int r = 0; r < 4; ++r) {
          st[t][r] = __expf(st[t][r] - mn);
          rs += st[t][r];
        }
      rs += __shfl_xor(rs, 16, 64);
      rs += __shfl_xor(rs, 32, 64);
      if (__any(rm > m)) {               // max grew: rescale O (exact: else
        const float alpha = __expf(m - mn);  // alpha==exp(0)==1, skip is
        lsum = lsum * alpha + rs;            // bit-identical)
        m = mn;
#pragma unroll
        for (int r = 0; r < 4; ++r) {
          const float ar = __shfl(alpha, quad * 4 + r, 64);
#pragma unroll
          for (int nt = 0; nt < 8; ++nt) o[nt][r] *= ar;
        }
      } else {
        lsum += rs;
      }
      const int prow = l16;
#pragma unroll
      for (int t = 0; t < 4; ++t) {
        bf16x4 pk = {(__bf16)st[t][0], (__bf16)st[t][1],
                     (__bf16)st[t][2], (__bf16)st[t][3]};
        const int wch = (t * 2 + (quad >> 1)) ^ (prow & 7);  // 16B-chunk swizzle
        *(bf16x4*)(Pw + prow * 128 + wch * 16 + (quad & 1) * 8) = pk;
      }
    }
    // ---- O += P V : per-wave P (no barrier) ----
    __builtin_amdgcn_s_setprio(1);
#pragma unroll
    for (int ks = 0; ks < 2; ++ks) {
      const int rch = ((ks * 4 + quad) ^ (l16 & 7)) << 4;   // swizzled 16B chunk
      bf16x8 pa = *(bf16x8*)(Pw + l16 * 128 + rch);
#pragma unroll
      for (int nt = 0; nt < 8; ++nt) {
        bf16x8 bv = *(bf16x8*)&Vs[(nt * 16 + l16) * 64 + (((ks * 4 + quad) ^ (l16 & 7)) << 3)];
        o[nt] = __builtin_amdgcn_mfma_f32_16x16x32_bf16(pa, bv, o[nt], 0, 0, 0);
      }
    }
    __builtin_amdgcn_s_setprio(0);
    // ---- end-of-tile: own LDS reads done, then free buf(kt^1) ----
    asm volatile("s_waitcnt lgkmcnt(0)" ::: "memory");
    __builtin_amdgcn_s_barrier();
    asm volatile("" ::: "memory");
  }
  // ---- epilogue: fused differential combine (loop-end barrier synced all) ----
  const float linv = 1.0f / lsum;
  if (w >= 4) {     // q-head 2hk+1: publish inv-scaled O
#pragma unroll
    for (int r = 0; r < 4; ++r) {
      const float inv = __shfl(linv, quad * 4 + r, 64);
      const int rr = wrow + quad * 4 + r;
#pragma unroll
      for (int nt = 0; nt < 8; ++nt)
        Ex[rr][nt * 16 + l16] = o[nt][r] * inv;
    }
  }
  __syncthreads();
  if (w < 4) {      // q-head 2hk: combine and write y
#pragma unroll
    for (int r = 0; r < 4; ++r) {
      const float inv = __shfl(linv, quad * 4 + r, 64);
      const int rr = wrow + quad * 4 + r;
      const int l = q0 + rr;
      const float lm = lam[l * 16 + hk];
      __bf16* dst = y + (size_t)l * 2048 + hk * 128;
#pragma unroll
      for (int nt = 0; nt < 8; ++nt) {
        const float v1 = o[nt][r] * inv;
        dst[nt * 16 + l16] = (__bf16)(v1 - lm * Ex[rr][nt * 16 + l16]);
      }
    }
  }
}

extern "C" void kernel_launch(void* const* d_in, const int* in_sizes, int n_in,
                              void* d_out, int out_size, void* d_ws, size_t ws_size,
                              hipStream_t stream) {
  const float* x     = (const float*)d_in[0];
  const float* W_DKV = (const float*)d_in[1];
  const float* W_UK  = (const float*)d_in[2];
  const float* W_UV  = (const float*)d_in[3];
  const float* W_DQ  = (const float*)d_in[4];
  const float* W_UQ  = (const float*)d_in[5];
  const float* W_lam = (const float*)d_in[6];
  const float* b_lam = (const float*)d_in[7];
  const float* W_out = (const float*)d_in[8];
  float* out = (float*)d_out;

  char* ws = (char*)d_ws;
  #define MB(n) ((size_t)(n) << 20)
  __bf16* x_bf   = (__bf16*)(ws + MB(0));    //  8 MB (2048x2048)
  __bf16* Wt_DKV = (__bf16*)(ws + MB(8));    //  2 MB (512x2048)
  __bf16* Wt_DQ  = (__bf16*)(ws + MB(10));   //  4 MB (1024x2048)
  __bf16* c_kv   = (__bf16*)(ws + MB(14));   //  2 MB (2048x512)
  __bf16* c_q    = (__bf16*)(ws + MB(16));   //  4 MB (2048x1024)
  __bf16* Wt_UK  = (__bf16*)(ws + MB(20));   //  2 MB (2048x512)
  __bf16* Wt_UV  = (__bf16*)(ws + MB(22));   //  2 MB (2048x512)
  __bf16* Wt_UQ  = (__bf16*)(ws + MB(24));   //  8 MB (4096x1024)
  __bf16* k_bf   = (__bf16*)(ws + MB(32));   //  8 MB (2048x2048) roped K
  __bf16* y_bf   = (__bf16*)(ws + MB(40));   //  8 MB (2048x2048)
  __bf16* q_bf   = (__bf16*)(ws + MB(48));   // 16 MB (2048x4096) un-roped
  __bf16* v_t    = (__bf16*)(ws + MB(64));   //  8 MB (2048x2048) V^T
  float*  lam    = (float*)(ws + MB(88));    // 128 KB
  float*  cosT   = (float*)(ws + MB(89));    //  1 MB
  float*  sinT   = (float*)(ws + MB(90));    //  1 MB
  __bf16* WlT    = (__bf16*)(ws + MB(91));   // 64 KB (16x2048)
  __bf16* Wt_out = (__bf16*)(ws + MB(92));   //  8 MB (2048x2048)  (total 100 MB)

  // prep: x cast + DKV/DQ transposes + WlT (only down_lam's inputs)
  prep_all<<<7296, 256, 0, stream>>>(W_DKV, W_DQ, x, W_lam,
                                     Wt_DKV, Wt_DQ, x_bf, WlT);
  // down-projections + lam + riders (UK/UV/UQ transposes, rope tables)
  down_lam<<<7584, 256, 0, stream>>>(x_bf, Wt_DKV, Wt_DQ, c_kv, c_q,
                                     WlT, b_lam, lam,
                                     W_UK, W_UV, W_UQ, Wt_UK, Wt_UV, Wt_UQ,
                                     cosT, sinT);
  // up-projections with fused epilogues: UK->roped k_bf, UV->v_t, UQ->q_bf
  up_fused3<<<dim3(64, 16), 256, 0, stream>>>(c_kv, Wt_UK, Wt_UV, c_q, Wt_UQ,
                                              k_bf, v_t, q_bf, cosT, sinT);
  // flash attention (512 blocks, R5 pairing) + W_out-transpose rider (2048)
  attn_kernel3<<<2560, 512, 0, stream>>>(q_bf, k_bf, v_t, cosT, sinT, lam,
                                         y_bf, W_out, Wt_out);
  // output projection, BM=64 BK=64 (512 blocks = 2/CU)
  gemm_mfma<64, 2, false><<<dim3(16, 32), 256, 0, stream>>>(y_bf, Wt_out, out, 2048, 2048, 2048);
}

// Round 13
// 277.009 us; speedup vs baseline: 1.1212x; 1.0410x over previous
//
#include <hip/hip_runtime.h>
#include <cstdint>
#include <cstddef>

typedef __bf16 bf16x8 __attribute__((ext_vector_type(8)));
typedef __bf16 bf16x4 __attribute__((ext_vector_type(4)));
typedef float f32x4 __attribute__((ext_vector_type(4)));

// ---------------------------------------------------------------------------
// Problem constants (B=1): D=2048, NH=16, DH=128, DC=512, DCQ=1024, L=2048
// ---------------------------------------------------------------------------

template <int N> __device__ __forceinline__ void waitcnt_vm() {
  if constexpr (N == 2)      asm volatile("s_waitcnt vmcnt(2)" ::: "memory");
  else if constexpr (N == 3) asm volatile("s_waitcnt vmcnt(3)" ::: "memory");
  else if constexpr (N == 4) asm volatile("s_waitcnt vmcnt(4)" ::: "memory");
  else if constexpr (N == 6) asm volatile("s_waitcnt vmcnt(6)" ::: "memory");
  else if constexpr (N == 8) asm volatile("s_waitcnt vmcnt(8)" ::: "memory");
  else                       asm volatile("s_waitcnt vmcnt(0)" ::: "memory");
}

// ---------------------------------------------------------------------------
// MFMA GEMM core: acc(BM x 128) += A(M,K) @ Bt(N,K)^T tile.  A,Bt row-major
// bf16.  BK = 32*NKS, NW waves (4 or 8), double-buffered LDS + counted-vmcnt
// pipeline.  NW=8 (512-thread blocks) for the small-grid BM=64 GEMMs —
// wave tile 32x32 (acc 2x2) halves per-wave density but DOUBLES waves/SIMD
// (down 1.6->3.25, out 2->4), the proven lever (R1/R5) for latency-bound
// GEMMs.  Per-output-element MFMA order unchanged -> bit-identical.
//  NW=4: BM=128 wave 64x64 (acc 4x4) / BM=64 wave 32x64 (acc 2x4).
//  NW=8: BM=64 wave 32x32 (acc 2x2).
// On return: all waves have passed the trailing barrier (LDS reusable).
// ---------------------------------------------------------------------------
template <int BM, int NKS, int NW>
__device__ __forceinline__ void gemm_core(const __bf16* __restrict__ A,
                                          const __bf16* __restrict__ Bt,
                                          int K, int bm, int bn,
                                          __bf16* As, __bf16* Bs,
                                          f32x4 (*acc)[128 / ((NW / 2) * 16)]) {
  const int tid = threadIdx.x;
  const int w = tid >> 6;
  const int lane = tid & 63;
  const int quad = lane >> 4;
  const int l16 = lane & 15;
  constexpr int WM = (BM == 128) ? 64 : 32;   // wave M extent
  constexpr int WN = 128 / (NW / 2);          // wave N extent (64 or 32)
  constexpr int MI = WM / 16;                 // acc rows (4 or 2)
  constexpr int NJ = WN / 16;                 // acc cols (4 or 2)
  const int wm = (w & 1) * WM;
  const int wn = (w >> 1) * WN;
  const int srow = lane >> 2;
  const int sseg = (lane & 3) * 8;

  // stage one BK-wide K-slice into LDS buffer `buf` (async).  Load groups
  // (16 rows x 1 KB each) are distributed round-robin across NW waves.
  auto stage = [&](int k0, int buf) {
#pragma unroll
    for (int ks = 0; ks < NKS; ++ks) {
#pragma unroll
      for (int g = w; g < BM / 16; g += NW) {  // A: BM/16 groups
        const __bf16* ga = A + (size_t)(bm + g * 16 + srow) * K + k0 + ks * 32 + sseg;
        __builtin_amdgcn_global_load_lds(
            (const __attribute__((address_space(1))) void*)ga,
            (__attribute__((address_space(3))) void*)&As[(buf * NKS + ks) * (BM * 32) + g * 512],
            16, 0, 0);
      }
#pragma unroll
      for (int g = w; g < 8; g += NW) {        // B: always 8 groups (128 rows)
        const __bf16* gb = Bt + (size_t)(bn + g * 16 + srow) * K + k0 + ks * 32 + sseg;
        __builtin_amdgcn_global_load_lds(
            (const __attribute__((address_space(1))) void*)gb,
            (__attribute__((address_space(3))) void*)&Bs[(buf * NKS + ks) * 4096 + g * 512],
            16, 0, 0);
      }
    }
  };

#pragma unroll
  for (int i = 0; i < MI; ++i)
#pragma unroll
    for (int j = 0; j < NJ; ++j) acc[i][j] = (f32x4){0.f, 0.f, 0.f, 0.f};

  // Drain any prologue VMEM so vmcnt counts only staging traffic.
  asm volatile("s_waitcnt vmcnt(0)" ::: "memory");
  stage(0, 0);

  const int NIT = K / (32 * NKS);
  for (int it = 0; it < NIT; ++it) {
    const int cur = it & 1;
    if (it + 1 < NIT) {
      stage((it + 1) * 32 * NKS, cur ^ 1);
      // wait for exactly THIS wave's current-tile loads; next-tile's stay
      // in flight across the barrier.
      if constexpr (NW == 4) {
        waitcnt_vm<NKS * (BM / 64 + 2)>();
      } else {  // NW=8, BM=64: waves 0..3 issued A+B (2/slice), 4..7 B only
        if (w < BM / 16) waitcnt_vm<NKS * 2>();
        else             waitcnt_vm<NKS * 1>();
      }
    } else {
      waitcnt_vm<0>();
    }
    __builtin_amdgcn_s_barrier();      // all waves' cur tiles staged
    asm volatile("" ::: "memory");     // pin LDS reads below the barrier
    const __bf16* Ab = &As[cur * NKS * (BM * 32)];
    const __bf16* Bb = &Bs[cur * NKS * 4096];
#pragma unroll
    for (int ks = 0; ks < NKS; ++ks) {
      bf16x8 af[MI], bfr[NJ];
#pragma unroll
      for (int i = 0; i < MI; ++i)
        af[i] = *(const bf16x8*)&Ab[ks * (BM * 32) + (wm + i * 16 + l16) * 32 + quad * 8];
#pragma unroll
      for (int j = 0; j < NJ; ++j)
        bfr[j] = *(const bf16x8*)&Bb[ks * 4096 + (wn + j * 16 + l16) * 32 + quad * 8];
#pragma unroll
      for (int i = 0; i < MI; ++i)
#pragma unroll
        for (int j = 0; j < NJ; ++j)
          acc[i][j] = __builtin_amdgcn_mfma_f32_16x16x32_bf16(af[i], bfr[j],
                                                              acc[i][j], 0, 0, 0);
    }
    // own LDS reads done, then free buf(cur) for stage(it+2)
    asm volatile("s_waitcnt lgkmcnt(0)" ::: "memory");
    __builtin_amdgcn_s_barrier();
    asm volatile("" ::: "memory");
  }
}

// plain epilogue: store acc to C (bf16 or f32), row-major ldc = N
template <int BM, int NKS, bool BF16OUT, int NW = 4>
__device__ __forceinline__ void gemm_body(const __bf16* __restrict__ A,
                                          const __bf16* __restrict__ Bt,
                                          void* __restrict__ Cv,
                                          int N, int K, int bm, int bn,
                                          __bf16* As, __bf16* Bs) {
  constexpr int WM = (BM == 128) ? 64 : 32;
  constexpr int WN = 128 / (NW / 2);
  constexpr int MI = WM / 16;
  constexpr int NJ = WN / 16;
  f32x4 acc[MI][NJ];
  gemm_core<BM, NKS, NW>(A, Bt, K, bm, bn, As, Bs, acc);
  const int tid = threadIdx.x;
  const int w = tid >> 6, lane = tid & 63, quad = lane >> 4, l16 = lane & 15;
  const int wm = (w & 1) * WM, wn = (w >> 1) * WN;
#pragma unroll
  for (int i = 0; i < MI; ++i)
#pragma unroll
    for (int j = 0; j < NJ; ++j)
#pragma unroll
      for (int r = 0; r < 4; ++r) {
        const int row = bm + wm + i * 16 + quad * 4 + r;
        const int col = bn + wn + j * 16 + l16;
        if constexpr (BF16OUT)
          ((__bf16*)Cv)[(size_t)row * N + col] = (__bf16)acc[i][j][r];
        else
          ((float*)Cv)[(size_t)row * N + col] = acc[i][j][r];
      }
}

template <int BM, int NKS, bool BF16OUT, int NW = 4>
__global__ __launch_bounds__(NW * 64) void gemm_mfma(const __bf16* __restrict__ A,
                                                     const __bf16* __restrict__ Bt,
                                                     void* __restrict__ Cv,
                                                     int M, int N, int K) {
  __shared__ __bf16 As[2 * BM * 32 * NKS];
  __shared__ __bf16 Bs[2 * 128 * 32 * NKS];
  gemm_body<BM, NKS, BF16OUT, NW>(A, Bt, Cv, N, K, blockIdx.y * BM, blockIdx.x * 128, As, Bs);
}

// 32x32 fp32->bf16 transpose tile helper (T is >=32x36 float scratch,
// st is a 256-thread sub-group index)
__device__ __forceinline__ void transpose_tile(const float* __restrict__ src,
                                               __bf16* __restrict__ dst,
                                               int K, int N, int kx, int ny,
                                               float (*T)[36], int st) {
  const int k0 = kx * 32;
  const int n0 = ny * 32;
  const int r = st >> 3;
  const int c = (st & 7) * 4;
  *(float4*)&T[r][c] = *(const float4*)&src[(size_t)(k0 + r) * N + n0 + c];
  __syncthreads();
  bf16x4 o = {(__bf16)T[c + 0][r], (__bf16)T[c + 1][r],
              (__bf16)T[c + 2][r], (__bf16)T[c + 3][r]};
  *(bf16x4*)&dst[(size_t)(n0 + r) * K + k0 + c] = o;
}

// ---------------------------------------------------------------------------
// down_lam (512 threads, 8 waves): down-projections (DKV 4 + DQ 8 col-tiles,
// BM=64 BK=64, NW=8 -> 3.25 waves/SIMD vs 1.6 at NW=4) + lam + riders:
// UK/UV/UQ weight transposes (6144 tiles, 2/block) and rope tables (4 rows
// /block, 512 blocks -> all 2048 rows; R11 bug was 256 blocks = half the
// table) — consumed only by up_fused3 (next launch; boundary orders them).
// 1D grid 4000: id<416 down/lam (bxl=id>>5, by=id&31; lam uses by<16);
// then 3072 transpose riders; then 512 rope riders.
// ---------------------------------------------------------------------------
__global__ __launch_bounds__(512) void down_lam(
    const __bf16* __restrict__ x_bf, const __bf16* __restrict__ WtDKV,
    const __bf16* __restrict__ WtDQ, __bf16* __restrict__ c_kv,
    __bf16* __restrict__ c_q, const __bf16* __restrict__ WlT,
    const float* __restrict__ b_lam, float* __restrict__ lam,
    const float* __restrict__ W_UK, const float* __restrict__ W_UV,
    const float* __restrict__ W_UQ, __bf16* __restrict__ tUK,
    __bf16* __restrict__ tUV, __bf16* __restrict__ tUQ,
    float* __restrict__ cosT, float* __restrict__ sinT) {
  __shared__ __bf16 As[2 * 64 * 32 * 2];     // 16 KB
  __shared__ __bf16 Bs[2 * 128 * 32 * 2];    // 32 KB
  int id = blockIdx.x;
  const int tid = threadIdx.x;
  if (id < 416) {
    const int bxl = id >> 5, by = id & 31;
    if (bxl == 12) {  // lam: 8 waves x 16 rows = 128 rows per by; by<16
      if (by >= 16) return;
      const int w = tid >> 6, lane = tid & 63, quad = lane >> 4, l16 = lane & 15;
      const int m0 = (by * 8 + w) * 16;
      const __bf16* xrow = x_bf + (size_t)(m0 + l16) * 2048 + quad * 8;
      const __bf16* wrow = WlT + (size_t)l16 * 2048 + quad * 8;
      f32x4 acc[4];
#pragma unroll
      for (int u = 0; u < 4; ++u) acc[u] = (f32x4){0.f, 0.f, 0.f, 0.f};
      for (int k0 = 0; k0 < 2048; k0 += 128) {
#pragma unroll
        for (int u = 0; u < 4; ++u) {
          bf16x8 a = *(const bf16x8*)&xrow[k0 + u * 32];
          bf16x8 b = *(const bf16x8*)&wrow[k0 + u * 32];
          acc[u] = __builtin_amdgcn_mfma_f32_16x16x32_bf16(a, b, acc[u], 0, 0, 0);
        }
      }
      const float bl = b_lam[l16];
#pragma unroll
      for (int r = 0; r < 4; ++r) {
        const float v = acc[0][r] + acc[1][r] + acc[2][r] + acc[3][r] + bl;
        lam[(size_t)(m0 + quad * 4 + r) * 16 + l16] = 1.0f / (1.0f + __expf(-v));
      }
      return;
    }
    if (bxl < 4)
      gemm_body<64, 2, true, 8>(x_bf, WtDKV, (void*)c_kv, 512, 2048,
                                by * 64, bxl * 128, As, Bs);
    else
      gemm_body<64, 2, true, 8>(x_bf, WtDQ, (void*)c_q, 1024, 2048,
                                by * 64, (bxl - 4) * 128, As, Bs);
    return;
  }
  id -= 416;
  if (id < 3072) {  // ---- UK/UV/UQ transpose riders: 2 tiles per block ----
    int t = id * 2 + (tid >> 8);
    const int st = tid & 255;
    float (*T)[36] = (float(*)[36])((char*)As + (tid >> 8) * 4608);
    if (t < 1024)
      transpose_tile(W_UK, tUK, 512, 2048, t & 15, t >> 4, T, st);
    else if (t < 2048) {
      t -= 1024;
      transpose_tile(W_UV, tUV, 512, 2048, t & 15, t >> 4, T, st);
    } else {
      t -= 2048;
      transpose_tile(W_UQ, tUQ, 1024, 4096, t & 31, t >> 5, T, st);
    }
    return;
  }
  id -= 3072;
  {  // ---- rope tables rider: 4 rows per block, 512 blocks = 2048 rows ----
    const int l = id * 4 + (tid >> 7);
    const int d = tid & 127;
    const int j = d & 63;
    const float inv = exp2f(-(float)j * 0.2076205059304601f);  // log2(1e4)/64
    const float ang = (float)l * inv;
    cosT[l * 128 + d] = cosf(ang);
    sinT[l * 128 + d] = sinf(ang);
  }
}

// ---------------------------------------------------------------------------
// up_fused3: up-projections UK/UV/UQ (BM=128 BK=32, NW=4 — already 4 waves/
// SIMD at 4 blocks/CU) with fused epilogues.
//  UK (bx<16):  K-RoPE applied in-epilogue (pairs d<->d^64 via LDS stash).
//  UV (bx<32):  V written directly TRANSPOSED to v_t[d][l].
//  UQ (else):   plain bf16 store to q_bf (roped later in attn).
// Grid dim3(64, 16).
// ---------------------------------------------------------------------------
__global__ __launch_bounds__(256) void up_fused3(
    const __bf16* __restrict__ c_kv, const __bf16* __restrict__ WtUK,
    const __bf16* __restrict__ WtUV, const __bf16* __restrict__ c_q,
    const __bf16* __restrict__ WtUQ, __bf16* __restrict__ k_bf,
    __bf16* __restrict__ v_t, __bf16* __restrict__ q_bf,
    const float* __restrict__ cosT, const float* __restrict__ sinT) {
  __shared__ __align__(16) char usm[32768];
  __bf16* As = (__bf16*)usm;             // 16 KB (2 buf x 128x32)
  __bf16* Bs = (__bf16*)(usm + 16384);   // 16 KB
  const int bx = blockIdx.x;
  const int bm = blockIdx.y * 128;
  const int tid = threadIdx.x;
  const int w = tid >> 6, lane = tid & 63, quad = lane >> 4, l16 = lane & 15;
  const int wm = (w & 1) * 64, wn = (w >> 1) * 64;
  f32x4 acc[4][4];
  if (bx < 16) {          // ---- UK -> roped K ----
    const int bn = bx * 128;   // head-aligned (128-wide heads)
    gemm_core<128, 1, 4>(c_kv, WtUK, 512, bm, bn, As, Bs, acc);
    // gemm_core's trailing barrier freed usm; stash bf16 tile for pairs
    __bf16 (*Kt)[128] = (__bf16(*)[128])usm;
#pragma unroll
    for (int i = 0; i < 4; ++i)
#pragma unroll
      for (int j = 0; j < 4; ++j)
#pragma unroll
        for (int r = 0; r < 4; ++r)
          Kt[wm + i * 16 + quad * 4 + r][wn + j * 16 + l16] = (__bf16)acc[i][j][r];
    __syncthreads();
#pragma unroll
    for (int j = 0; j < 4; ++j) {
      const int d = wn + j * 16 + l16;
      const float sgn = (d < 64) ? -1.f : 1.f;
#pragma unroll
      for (int i = 0; i < 4; ++i)
#pragma unroll
        for (int r = 0; r < 4; ++r) {
          const int lr = wm + i * 16 + quad * 4 + r;
          const int l = bm + lr;
          const float v = (float)Kt[lr][d];        // == bf16(acc), as before
          const float pr = (float)Kt[lr][d ^ 64];
          const float ov = v * cosT[l * 128 + d] + sgn * pr * sinT[l * 128 + d];
          k_bf[(size_t)l * 2048 + bn + d] = (__bf16)ov;
        }
    }
  } else if (bx < 32) {   // ---- UV -> transposed V ----
    const int bn = (bx - 16) * 128;
    gemm_core<128, 1, 4>(c_kv, WtUV, 512, bm, bn, As, Bs, acc);
#pragma unroll
    for (int i = 0; i < 4; ++i)
#pragma unroll
      for (int j = 0; j < 4; ++j) {
        const int d = bn + wn + j * 16 + l16;       // global dim = v_t row
        const int l = bm + wm + i * 16 + quad * 4;  // 4 consecutive l
        bf16x4 pk = {(__bf16)acc[i][j][0], (__bf16)acc[i][j][1],
                     (__bf16)acc[i][j][2], (__bf16)acc[i][j][3]};
        *(bf16x4*)&v_t[(size_t)d * 2048 + l] = pk;
      }
  } else {                // ---- UQ -> plain q_bf ----
    const int bn = (bx - 32) * 128;
    gemm_core<128, 1, 4>(c_q, WtUQ, 1024, bm, bn, As, Bs, acc);
#pragma unroll
    for (int i = 0; i < 4; ++i)
#pragma unroll
      for (int j = 0; j < 4; ++j)
#pragma unroll
        for (int r = 0; r < 4; ++r) {
          const int row = bm + wm + i * 16 + quad * 4 + r;
          const int col = bn + wn + j * 16 + l16;
          q_bf[(size_t)row * 4096 + col] = (__bf16)acc[i][j][r];
        }
  }
}

// ---------------------------------------------------------------------------
// prep_all: x cast + DKV/DQ weight transposes + W_lam transpose (only what
// down_lam needs; UK/UV/UQ transposes + rope tables ride down_lam's launch,
// W_out transpose rides attn's).  Grid 7296.
// ---------------------------------------------------------------------------
__global__ __launch_bounds__(256) void prep_all(
    const float* __restrict__ W_DKV, const float* __restrict__ W_DQ,
    const float* __restrict__ x,     const float* __restrict__ W_lam,
    __bf16* __restrict__ tDKV, __bf16* __restrict__ tDQ,
    __bf16* __restrict__ x_bf, __bf16* __restrict__ WlT) {
  __shared__ float T[32][36];
  int t = blockIdx.x;
  const int tid = threadIdx.x;
  if (t < 3072) {
    if (t < 1024)
      transpose_tile(W_DKV, tDKV, 2048, 512, t & 63, t >> 6, T, tid);
    else {
      t -= 1024;
      transpose_tile(W_DQ, tDQ, 2048, 1024, t & 63, t >> 6, T, tid);
    }
    return;
  }
  t -= 3072;
  if (t < 4096) {  // x cast: 4096 blocks x 1024 floats
    const int i = t * 256 + tid;
    float4 v = *(const float4*)&x[(size_t)i * 4];
    bf16x4 o = {(__bf16)v.x, (__bf16)v.y, (__bf16)v.z, (__bf16)v.w};
    *(bf16x4*)&x_bf[(size_t)i * 4] = o;
    return;
  }
  t -= 4096;
  {  // W_lam (2048,16) -> WlT (16,2048) bf16: 128 blocks
    const int i = t * 256 + tid;
    const int k = i >> 4, n = i & 15;
    WlT[(size_t)n * 2048 + k] = (__bf16)W_lam[i];
  }
}

// ---------------------------------------------------------------------------
// MFMA flash attention, 512-thread blocks (8 waves), double-buffered K/V,
// counted-vmcnt pipeline + setprio.  Wave w (0..7) owns 16 q-rows of head
// (w>>2) — 16 waves/CU = 4/SIMD.  R5 pairing (qt pairs sum to 31; bx and
// bx+256 co-reside at 2 blocks/CU).  Exact defer-rescale (alpha==1 skip).
//  bx < 512: attn.  bx >= 512: W_out transpose rider (2 tiles/block).
//  LDS = 81920 B (2 blocks/CU): buf0/buf1 K 64x128 + V^T 128x64 + per-wave P.
// ---------------------------------------------------------------------------
__global__ __launch_bounds__(512, 2) void attn_kernel3(
    const __bf16* __restrict__ Qb, const __bf16* __restrict__ Kb,
    const __bf16* __restrict__ Vt, const float* __restrict__ cosT,
    const float* __restrict__ sinT, const float* __restrict__ lam,
    __bf16* __restrict__ y, const float* __restrict__ W_out,
    __bf16* __restrict__ Wt_out) {
  __shared__ __align__(16) char smem[81920];
  float (*Ex)[132] = (float(*)[132])smem;              // epilogue union (33.8 KB)

  const int bx = blockIdx.x;
  const int tid = threadIdx.x;
  if (bx >= 512) {  // ---- W_out transpose rider: 2 32x32 tiles per block ----
    const int t = (bx - 512) * 2 + (tid >> 8);
    const int st = tid & 255;
    float (*T)[36] = (float(*)[36])(smem + (tid >> 8) * 4608);
    const int k0 = (t & 63) * 32;
    const int n0 = (t >> 6) * 32;
    const int r = st >> 3;
    const int c = (st & 7) * 4;
    *(float4*)&T[r][c] = *(const float4*)&W_out[(size_t)(k0 + r) * 2048 + n0 + c];
    __syncthreads();
    bf16x4 o = {(__bf16)T[c + 0][r], (__bf16)T[c + 1][r],
                (__bf16)T[c + 2][r], (__bf16)T[c + 3][r]};
    *(bf16x4*)&Wt_out[(size_t)(n0 + r) * 2048 + k0 + c] = o;
    return;
  }
  const int hv = bx >> 8;
  const int ii = bx & 255;
  const int qt = hv ? (ii >> 4) : 31 - (ii >> 4);  // pairs (31-k, k) per CU
  const int hk = ii & 15;
  const int q0 = qt * 64;
  const int w = tid >> 6, lane = tid & 63, quad = lane >> 4, l16 = lane & 15;
  const int wrow = (w & 3) * 16;              // wave's 16-row group
  const int qoff = (2 * hk + (w >> 2)) * 128; // wave's q-head
  const int kvoff = hk * 128;
  const float qscale = 0.08838834764831845f;  // 1/sqrt(128), folded into Q
  char* Pw = smem + 65536 + w * 2048;         // 16 rows x 128 B per wave

  // ---- Q fragment + RoPE + scale in-register (one 16-row subtile) ----
  bf16x8 aq[4];
  {
    const int l = q0 + wrow + l16;
    const size_t qbase = (size_t)l * 4096 + qoff + quad * 8;
    bf16x8 raw[4];
#pragma unroll
    for (int ks = 0; ks < 4; ++ks)
      raw[ks] = *(const bf16x8*)&Qb[qbase + ks * 32];
#pragma unroll
    for (int ks = 0; ks < 4; ++ks) {
      const float* cp = &cosT[l * 128 + ks * 32 + quad * 8];
      const float* sp = &sinT[l * 128 + ks * 32 + quad * 8];
#pragma unroll
      for (int j = 0; j < 8; ++j) {
        const float cv = cp[j];
        const float sv = sp[j];
        const float rot = (ks < 2) ? -(float)raw[ks + 2][j] : (float)raw[ks - 2][j];
        aq[ks][j] = (__bf16)(((float)raw[ks][j] * cv + rot * sv) * qscale);
      }
    }
  }

  // ---- staging helper: 4 global_load_lds per wave into chosen buffer ----
  auto stage = [&](int kt_, char* buf) {
    const int k0_ = kt_ * 64;
    __bf16* Ksb = (__bf16*)buf;
    __bf16* Vsb = (__bf16*)(buf + 16384);
#pragma unroll
    for (int d = 0; d < 2; ++d) {
      const int r0 = w * 8 + d * 4;              // 4 K-rows per DMA
      const int row = r0 + (lane >> 4);
      const int ck = (lane & 15) ^ (row & 15);
      const __bf16* ga = Kb + (size_t)(k0_ + row) * 2048 + kvoff + ck * 8;
      __builtin_amdgcn_global_load_lds(
          (const __attribute__((address_space(1))) void*)ga,
          (__attribute__((address_space(3))) void*)&Ksb[r0 * 128], 16, 0, 0);
      const int r0v = w * 16 + d * 8;            // 8 V-rows per DMA
      const int rowv = r0v + (lane >> 3);
      const int cv = (lane & 7) ^ (rowv & 7);
      const __bf16* gv = Vt + (size_t)(kvoff + rowv) * 2048 + k0_ + cv * 8;
      __builtin_amdgcn_global_load_lds(
          (const __attribute__((address_space(1))) void*)gv,
          (__attribute__((address_space(3))) void*)&Vsb[r0v * 64], 16, 0, 0);
    }
  };

  f32x4 o[8];
#pragma unroll
  for (int i = 0; i < 8; ++i) o[i] = (f32x4){0.f, 0.f, 0.f, 0.f};
  float m = -1e30f, lsum = 0.f;

  // Drain Q/rope loads so vmcnt counts only staging traffic, then prologue.
  asm volatile("s_waitcnt vmcnt(0)" ::: "memory");
  stage(0, smem);

  for (int kt = 0; kt <= qt; ++kt) {
    const int cur = kt & 1;
    __bf16* Ks = (__bf16*)(smem + cur * 32768);
    __bf16* Vs = (__bf16*)(smem + cur * 32768 + 16384);
    const int k0 = kt * 64;
    if (kt < qt) {
      stage(kt + 1, smem + (cur ^ 1) * 32768);
      asm volatile("s_waitcnt vmcnt(4)" ::: "memory");  // kt's 4 loads done
    } else {
      asm volatile("s_waitcnt vmcnt(0)" ::: "memory");
    }
    __builtin_amdgcn_s_barrier();        // all waves' kt tiles staged
    asm volatile("" ::: "memory");       // pin LDS reads below the barrier
    // ---- S^T = K Q^T : 4 key m-tiles x 4 k-steps ----
    f32x4 st[4];
#pragma unroll
    for (int t = 0; t < 4; ++t) st[t] = (f32x4){0.f, 0.f, 0.f, 0.f};
    __builtin_amdgcn_s_setprio(1);
#pragma unroll
    for (int ks = 0; ks < 4; ++ks) {
#pragma unroll
      for (int t = 0; t < 4; ++t) {
        bf16x8 ak = *(bf16x8*)&Ks[(t * 16 + l16) * 128 + (((ks * 4 + quad) ^ l16) << 3)];
        st[t] = __builtin_amdgcn_mfma_f32_16x16x32_bf16(ak, aq[ks], st[t], 0, 0, 0);
      }
    }
    __builtin_amdgcn_s_setprio(0);
    // ---- online softmax (scale pre-folded into Q) ----
    {
      const int q = q0 + wrow + l16;
      float rm = -1e30f;
      if (kt != qt) {
#pragma unroll
        for (int t = 0; t < 4; ++t)
#pragma unroll
          for (int r = 0; r < 4; ++r) rm = fmaxf(rm, st[t][r]);
      } else {
#pragma unroll
        for (int t = 0; t < 4; ++t)
#pragma unroll
          for (int r = 0; r < 4; ++r) {
            const int key = k0 + t * 16 + quad * 4 + r;
            if (key > q) st[t][r] = -1e30f;
            rm = fmaxf(rm, st[t][r]);
          }
      }
      rm = fmaxf(rm, __shfl_xor(rm, 16, 64));
      rm = fmaxf(rm, __shfl_xor(rm, 32, 64));
      const float mn = fmaxf(m, rm);
      float rs = 0.f;
#pragma unroll
      for (int t = 0; t < 4; ++t)
#pragma unroll
        for (int r = 0; r < 4; ++r) {
          st[t][r] = __expf(st[t][r] - mn);
          rs += st[t][r];
        }
      rs += __shfl_xor(rs, 16, 64);
      rs += __shfl_xor(rs, 32, 64);
      if (__any(rm > m)) {               // max grew: rescale O (exact: else
        const float alpha = __expf(m - mn);  // alpha==exp(0)==1, skip is
        lsum = lsum * alpha + rs;            // bit-identical)
        m = mn;
#pragma unroll
        for (int r = 0; r < 4; ++r) {
          const float ar = __shfl(alpha, quad * 4 + r, 64);
#pragma unroll
          for (int nt = 0; nt < 8; ++nt) o[nt][r] *= ar;
        }
      } else {
        lsum += rs;
      }
      const int prow = l16;
#pragma unroll
      for (int t = 0; t < 4; ++t) {
        bf16x4 pk = {(__bf16)st[t][0], (__bf16)st[t][1],
                     (__bf16)st[t][2], (__bf16)st[t][3]};
        const int wch = (t * 2 + (quad >> 1)) ^ (prow & 7);  // 16B-chunk swizzle
        *(bf16x4*)(Pw + prow * 128 + wch * 16 + (quad & 1) * 8) = pk;
      }
    }
    // ---- O += P V : per-wave P (no barrier) ----
    __builtin_amdgcn_s_setprio(1);
#pragma unroll
    for (int ks = 0; ks < 2; ++ks) {
      const int rch = ((ks * 4 + quad) ^ (l16 & 7)) << 4;   // swizzled 16B chunk
      bf16x8 pa = *(bf16x8*)(Pw + l16 * 128 + rch);
#pragma unroll
      for (int nt = 0; nt < 8; ++nt) {
        bf16x8 bv = *(bf16x8*)&Vs[(nt * 16 + l16) * 64 + (((ks * 4 + quad) ^ (l16 & 7)) << 3)];
        o[nt] = __builtin_amdgcn_mfma_f32_16x16x32_bf16(pa, bv, o[nt], 0, 0, 0);
      }
    }
    __builtin_amdgcn_s_setprio(0);
    // ---- end-of-tile: own LDS reads done, then free buf(kt^1) ----
    asm volatile("s_waitcnt lgkmcnt(0)" ::: "memory");
    __builtin_amdgcn_s_barrier();
    asm volatile("" ::: "memory");
  }
  // ---- epilogue: fused differential combine (loop-end barrier synced all) ----
  const float linv = 1.0f / lsum;
  if (w >= 4) {     // q-head 2hk+1: publish inv-scaled O
#pragma unroll
    for (int r = 0; r < 4; ++r) {
      const float inv = __shfl(linv, quad * 4 + r, 64);
      const int rr = wrow + quad * 4 + r;
#pragma unroll
      for (int nt = 0; nt < 8; ++nt)
        Ex[rr][nt * 16 + l16] = o[nt][r] * inv;
    }
  }
  __syncthreads();
  if (w < 4) {      // q-head 2hk: combine and write y
#pragma unroll
    for (int r = 0; r < 4; ++r) {
      const float inv = __shfl(linv, quad * 4 + r, 64);
      const int rr = wrow + quad * 4 + r;
      const int l = q0 + rr;
      const float lm = lam[l * 16 + hk];
      __bf16* dst = y + (size_t)l * 2048 + hk * 128;
#pragma unroll
      for (int nt = 0; nt < 8; ++nt) {
        const float v1 = o[nt][r] * inv;
        dst[nt * 16 + l16] = (__bf16)(v1 - lm * Ex[rr][nt * 16 + l16]);
      }
    }
  }
}

extern "C" void kernel_launch(void* const* d_in, const int* in_sizes, int n_in,
                              void* d_out, int out_size, void* d_ws, size_t ws_size,
                              hipStream_t stream) {
  const float* x     = (const float*)d_in[0];
  const float* W_DKV = (const float*)d_in[1];
  const float* W_UK  = (const float*)d_in[2];
  const float* W_UV  = (const float*)d_in[3];
  const float* W_DQ  = (const float*)d_in[4];
  const float* W_UQ  = (const float*)d_in[5];
  const float* W_lam = (const float*)d_in[6];
  const float* b_lam = (const float*)d_in[7];
  const float* W_out = (const float*)d_in[8];
  float* out = (float*)d_out;

  char* ws = (char*)d_ws;
  #define MB(n) ((size_t)(n) << 20)
  __bf16* x_bf   = (__bf16*)(ws + MB(0));    //  8 MB (2048x2048)
  __bf16* Wt_DKV = (__bf16*)(ws + MB(8));    //  2 MB (512x2048)
  __bf16* Wt_DQ  = (__bf16*)(ws + MB(10));   //  4 MB (1024x2048)
  __bf16* c_kv   = (__bf16*)(ws + MB(14));   //  2 MB (2048x512)
  __bf16* c_q    = (__bf16*)(ws + MB(16));   //  4 MB (2048x1024)
  __bf16* Wt_UK  = (__bf16*)(ws + MB(20));   //  2 MB (2048x512)
  __bf16* Wt_UV  = (__bf16*)(ws + MB(22));   //  2 MB (2048x512)
  __bf16* Wt_UQ  = (__bf16*)(ws + MB(24));   //  8 MB (4096x1024)
  __bf16* k_bf   = (__bf16*)(ws + MB(32));   //  8 MB (2048x2048) roped K
  __bf16* y_bf   = (__bf16*)(ws + MB(40));   //  8 MB (2048x2048)
  __bf16* q_bf   = (__bf16*)(ws + MB(48));   // 16 MB (2048x4096) un-roped
  __bf16* v_t    = (__bf16*)(ws + MB(64));   //  8 MB (2048x2048) V^T
  float*  lam    = (float*)(ws + MB(88));    // 128 KB
  float*  cosT   = (float*)(ws + MB(89));    //  1 MB
  float*  sinT   = (float*)(ws + MB(90));    //  1 MB
  __bf16* WlT    = (__bf16*)(ws + MB(91));   // 64 KB (16x2048)
  __bf16* Wt_out = (__bf16*)(ws + MB(92));   //  8 MB (2048x2048)  (total 100 MB)

  // prep: x cast + DKV/DQ transposes + WlT (only down_lam's inputs)
  prep_all<<<7296, 256, 0, stream>>>(W_DKV, W_DQ, x, W_lam,
                                     Wt_DKV, Wt_DQ, x_bf, WlT);
  // down-projections (NW=8, 512 threads) + lam + riders (UK/UV/UQ
  // transposes 2/block, rope tables 4 rows/block x 512 blocks)
  down_lam<<<4000, 512, 0, stream>>>(x_bf, Wt_DKV, Wt_DQ, c_kv, c_q,
                                     WlT, b_lam, lam,
                                     W_UK, W_UV, W_UQ, Wt_UK, Wt_UV, Wt_UQ,
                                     cosT, sinT);
  // up-projections with fused epilogues: UK->roped k_bf, UV->v_t, UQ->q_bf
  up_fused3<<<dim3(64, 16), 256, 0, stream>>>(c_kv, Wt_UK, Wt_UV, c_q, Wt_UQ,
                                              k_bf, v_t, q_bf, cosT, sinT);
  // flash attention (512 blocks, R5 pairing) + W_out-transpose rider (2048)
  attn_kernel3<<<2560, 512, 0, stream>>>(q_bf, k_bf, v_t, cosT, sinT, lam,
                                         y_bf, W_out, Wt_out);
  // output projection, BM=64 BK=64, NW=8 (512 blocks x 8 waves = 4/SIMD)
  gemm_mfma<64, 2, false, 8><<<dim3(16, 32), 512, 0, stream>>>(y_bf, Wt_out, out, 2048, 2048, 2048);
}